// Round 7
// baseline (386.646 us; speedup 1.0000x reference)
//
#include <hip/hip_runtime.h>
#include <hip/hip_bf16.h>

// Problem dims (fixed)
#define BB 8
#define TT 1024
#define DD 1024
#define HH 16
#define AA 64
#define EE 262144

typedef unsigned short u16;
typedef unsigned int u32;
typedef short bf16x4 __attribute__((ext_vector_type(4)));
typedef short bf16x8 __attribute__((ext_vector_type(8)));
typedef float f32x4 __attribute__((ext_vector_type(4)));

__device__ __forceinline__ float bf2f(u16 u) {
    union { float f; u32 i; } c; c.i = ((u32)u) << 16; return c.f;
}
__device__ __forceinline__ u16 f2bf(float f) {
    union { float f; u32 i; } c; c.f = f;
    u32 x = c.i;
    return (u16)((x + 0x7FFFu + ((x >> 16) & 1u)) >> 16);
}
// packed 2xf32 -> 2xbf16 (v_cvt_pk_bf16_f32 on gfx950)
__device__ __forceinline__ u32 pack2bf(float a, float b) {
    union { __hip_bfloat162 h; u32 u; } c;
    c.h = __float22bfloat162_rn(float2{a, b});
    return c.u;
}
// native exp2 (v_exp_f32)
__device__ __forceinline__ float fast_exp2(float x) {
#if __has_builtin(__builtin_amdgcn_exp2f)
    return __builtin_amdgcn_exp2f(x);
#else
    float r;
    asm("v_exp_f32 %0, %1" : "=v"(r) : "v"(x));
    return r;
#endif
}

// log2(e) folded scales: softmax computed as exp2( log2e * (s/8 + bias*ksum/8 - 20) )
#define QSCALE 0.18033688f          // 0.125 * 1.44269504
#define SOFT_OFF -28.8539008f       // -20 * 1.44269504

// async 16B global->LDS (per-lane gptr; LDS dest = wave-uniform base + lane*16)
#define GLDS16(gp, lp)                                                        \
    __builtin_amdgcn_global_load_lds(                                         \
        (const __attribute__((address_space(1))) u32*)(const void*)(gp),      \
        (__attribute__((address_space(3))) u32*)(void*)(lp), 16, 0, 0)

#define MFMA(a, b, c) __builtin_amdgcn_mfma_f32_16x16x32_bf16((a), (b), (c), 0, 0, 0)

// ---------------------------------------------------------------------------
// prep1: fused independent prep work, partitioned by blockIdx.x
//  [0,4096)      cvt states -> sbf
//  [4096,8192)   cvt key_states -> kbf
//  [8192,12288)  mbinit (masks -> bf16 mb)
//  [12288,16384) idx init (-1)
//  [16384,17408) tr_w (4x 1024x1024 f32 -> bf16 transposed)
// ---------------------------------------------------------------------------
__global__ __launch_bounds__(256) void prep1(const float* __restrict__ states,
                                             const float* __restrict__ keys,
                                             const float* __restrict__ masks,
                                             const float* __restrict__ Wq,
                                             const float* __restrict__ Wk,
                                             const float* __restrict__ Wv,
                                             const float* __restrict__ Wout,
                                             u16* __restrict__ sbf,
                                             u16* __restrict__ kbf,
                                             u16* __restrict__ mb,
                                             int* __restrict__ idx,
                                             u16* __restrict__ wT) {
    __shared__ u16 t[64 * 72];
    int bi = blockIdx.x, tid = threadIdx.x;
    if (bi < 12288) {
        if (bi < 8192) {  // cvt
            const float* src = (bi < 4096) ? states : keys;
            u16* dst = (bi < 4096) ? sbf : kbf;
            size_t i = ((size_t)(bi & 4095) * 256 + tid) * 8;
            f32x4 a = *(const f32x4*)(src + i);
            f32x4 b = *(const f32x4*)(src + i + 4);
            u32 o[4];
            o[0] = pack2bf(a[0], a[1]);
            o[1] = pack2bf(a[2], a[3]);
            o[2] = pack2bf(b[0], b[1]);
            o[3] = pack2bf(b[2], b[3]);
            *(bf16x8*)(dst + i) = *(bf16x8*)o;
        } else {  // mbinit
            size_t i = ((size_t)(bi - 8192) * 256 + tid) * 8;
            f32x4 a = *(const f32x4*)(masks + i);
            f32x4 b = *(const f32x4*)(masks + i + 4);
            const u16 M = f2bf(-1.0e30f);
            bf16x8 o;
#pragma unroll
            for (int j = 0; j < 4; j++) {
                o[j] = (short)((a[j] != 0.f) ? M : 0);
                o[4 + j] = (short)((b[j] != 0.f) ? M : 0);
            }
            *(bf16x8*)(mb + i) = o;
        }
    } else if (bi < 16384) {  // idx init
        size_t i = ((size_t)(bi - 12288) * 256 + tid) * 8;
        int4 m1 = {-1, -1, -1, -1};
        *(int4*)(idx + i) = m1;
        *(int4*)(idx + i + 4) = m1;
    } else {  // tr_w
        int zb = bi - 16384;
        int z = zb >> 8, by = (zb >> 4) & 15, bx = zb & 15;
        const float* src = (z == 0) ? Wq : (z == 1) ? Wk : (z == 2) ? Wv : Wout;
        u16* dst = wT + (size_t)z * 1048576;
        int row0 = by * 64, col0 = bx * 64;
        int r = tid >> 2, c0 = (tid & 3) * 16;
        const float* sp = src + (size_t)(row0 + r) * 1024 + col0 + c0;
        f32x4 f0 = *(const f32x4*)(sp);
        f32x4 f1 = *(const f32x4*)(sp + 4);
        f32x4 f2_ = *(const f32x4*)(sp + 8);
        f32x4 f3 = *(const f32x4*)(sp + 12);
#pragma unroll
        for (int j = 0; j < 4; j++) {
            t[r * 72 + c0 + j] = f2bf(f0[j]);
            t[r * 72 + c0 + 4 + j] = f2bf(f1[j]);
            t[r * 72 + c0 + 8 + j] = f2bf(f2_[j]);
            t[r * 72 + c0 + 12 + j] = f2bf(f3[j]);
        }
        __syncthreads();
        bf16x8 o0, o1;
#pragma unroll
        for (int j = 0; j < 8; j++) o0[j] = (short)t[(c0 + j) * 72 + r];
#pragma unroll
        for (int j = 0; j < 8; j++) o1[j] = (short)t[(c0 + 8 + j) * 72 + r];
        *(bf16x8*)(dst + (size_t)(col0 + r) * 1024 + row0 + c0) = o0;
        *(bf16x8*)(dst + (size_t)(col0 + r) * 1024 + row0 + c0 + 8) = o1;
    }
}

// ---------------------------------------------------------------------------
// scatter pass 1 — last edge index wins (numpy semantics)
// ---------------------------------------------------------------------------
__global__ __launch_bounds__(256) void scat_max(const int* __restrict__ ab,
                                                int* __restrict__ idx) {
    int e = blockIdx.x * 256 + threadIdx.x;
    int4 rec = ((const int4*)ab)[e];
    atomicMax(&idx[((((size_t)rec.y << 10) + rec.z) << 10) + rec.w], e);
}

// scatter pass 2 — winner writes prescaled bf16 value (skip masked cells)
// proj prescaled by 0.125 * log2(e) to match exp2-based softmax.
__global__ __launch_bounds__(256) void scat_res(const int* __restrict__ ab,
                                                const int* __restrict__ idx,
                                                const float* __restrict__ be,
                                                const float* __restrict__ bsc,
                                                u16* __restrict__ mb) {
    __shared__ float proj[32];
    int tid = threadIdx.x;
    if (tid < 32) {
        float s = 0.f;
        for (int a = 0; a < 64; a++) s += be[tid * 64 + a] * bsc[a];
        proj[tid] = s * QSCALE;  // fold 1/sqrt(A) * log2(e)
    }
    __syncthreads();
    int e = blockIdx.x * 256 + tid;
    int4 rec = ((const int4*)ab)[e];
    size_t cell = ((((size_t)rec.y << 10) + rec.z) << 10) + rec.w;
    if (idx[cell] == e && bf2f(mb[cell]) > -1.0e29f) mb[cell] = f2bf(proj[rec.x]);
}

// ---------------------------------------------------------------------------
// gemm5: fused QKV projection. grid (24,64): mat = x>>3 (0=Q,1=K,2=V).
// 128x128 tile, BK=64, both operands via global_load_lds w/ global-side XOR
// chunk swizzle (conflict-free unpadded LDS reads).
// mat 0: qb [B,H,T,A] bf16, scaled 0.125*log2e (exp2 softmax).
// mat 1: kb [B,H,T,A] bf16 + ksum f32 (shuffle-reduced in epilogue).
// mat 2: vT [B,H,A,T] bf16 via LDS transpose epilogue.
// ---------------------------------------------------------------------------
__global__ __launch_bounds__(256) void gemm5(const u16* __restrict__ sbf,
                                             const u16* __restrict__ kbf,
                                             const u16* __restrict__ wT,
                                             u16* __restrict__ qb,
                                             u16* __restrict__ kb,
                                             u16* __restrict__ vT,
                                             float* __restrict__ ks) {
    __shared__ u16 smem[17408];  // 34816 B: staging [0,16384) u16, transpose 128x136
    int tid = threadIdx.x;
    int wave = tid >> 6, lane = tid & 63;
    int quad = lane >> 4, l16 = lane & 15;
    int wm = wave >> 1, wn = wave & 1;
    int mat = blockIdx.x >> 3;
    int nloc = (blockIdx.x & 7) * 128;
    int mbase = blockIdx.y * 128;
    const u16* A = (mat == 0) ? sbf : kbf;
    const u16* BT = wT + (size_t)mat * 1048576;
    u16* Asm = smem;
    u16* Bsm = smem + 8192;
    f32x4 acc[4][4] = {};
    int srow = wave * 32 + (lane >> 3);
    int schunk = (lane & 7) ^ (lane >> 3);
    const u16* gA = A + (size_t)(mbase + srow) * 1024 + schunk * 8;
    const u16* gB = BT + (size_t)(nloc + srow) * 1024 + schunk * 8;
    u16* lA = Asm + wave * 2048;
    u16* lB = Bsm + wave * 2048;
    int sx = l16 & 7;
    for (int k0 = 0; k0 < 1024; k0 += 64) {
        __syncthreads();
#pragma unroll
        for (int j = 0; j < 4; j++) GLDS16(gA + k0 + j * 8192, lA + j * 512);
#pragma unroll
        for (int j = 0; j < 4; j++) GLDS16(gB + k0 + j * 8192, lB + j * 512);
        __syncthreads();
#pragma unroll
        for (int kk = 0; kk < 2; kk++) {
            bf16x8 af[4], bfr[4];
#pragma unroll
            for (int mt = 0; mt < 4; mt++)
                af[mt] = *(const bf16x8*)&Asm[(wm * 64 + mt * 16 + l16) * 64 +
                                              ((kk * 4 + quad) ^ sx) * 8];
#pragma unroll
            for (int nt = 0; nt < 4; nt++)
                bfr[nt] = *(const bf16x8*)&Bsm[(wn * 64 + nt * 16 + l16) * 64 +
                                               ((kk * 4 + quad) ^ sx) * 8];
#pragma unroll
            for (int mt = 0; mt < 4; mt++)
#pragma unroll
                for (int nt = 0; nt < 4; nt++)
                    acc[mt][nt] = MFMA(af[mt], bfr[nt], acc[mt][nt]);
        }
    }

    if (mat == 2) {
        // V: transpose through LDS -> vT [B,H,A,T]
        __syncthreads();  // all waves done with staging LDS
#pragma unroll
        for (int mt = 0; mt < 4; mt++)
#pragma unroll
            for (int nt = 0; nt < 4; nt++)
#pragma unroll
                for (int r = 0; r < 4; r++) {
                    int rowl = wm * 64 + mt * 16 + quad * 4 + r;
                    int coll = wn * 64 + nt * 16 + l16;
                    smem[coll * 136 + rowl] = f2bf(acc[mt][nt][r]);
                }
        __syncthreads();
        int b = mbase >> 10, t0 = mbase & 1023;
        int c = tid >> 1, hf = tid & 1;
        int h = (nloc >> 6) + (c >> 6);
        int a = c & 63;
        u16* dst = vT + ((((size_t)(b * 16 + h)) * 64 + a) << 10) + t0 + hf * 64;
        const u16* srcl = smem + c * 136 + hf * 64;
#pragma unroll
        for (int j = 0; j < 8; j++) *(bf16x8*)(dst + j * 8) = *(const bf16x8*)(srcl + j * 8);
    } else {
        u16* dst = (mat == 0) ? qb : kb;
        float sc = (mat == 0) ? QSCALE : 1.0f;
#pragma unroll
        for (int mt = 0; mt < 4; mt++)
#pragma unroll
            for (int nt = 0; nt < 4; nt++)
#pragma unroll
                for (int r = 0; r < 4; r++) {
                    int gm = mbase + wm * 64 + mt * 16 + quad * 4 + r;
                    int gnl = nloc + wn * 64 + nt * 16 + l16;
                    int b = gm >> 10, t = gm & 1023, h = gnl >> 6, a = gnl & 63;
                    dst[(((size_t)(b * 16 + h) * 1024) + t) * 64 + a] =
                        f2bf(acc[mt][nt][r] * sc);
                }
        if (mat == 1) {
            // ksum[b,h,t] = sum_a K (f32 acc, pre-rounding)
            int h = (nloc + wn * 64) >> 6;
#pragma unroll
            for (int mt = 0; mt < 4; mt++)
#pragma unroll
                for (int r = 0; r < 4; r++) {
                    float s = acc[mt][0][r] + acc[mt][1][r] + acc[mt][2][r] + acc[mt][3][r];
                    s += __shfl_xor(s, 1);
                    s += __shfl_xor(s, 2);
                    s += __shfl_xor(s, 4);
                    s += __shfl_xor(s, 8);
                    if (l16 == 0) {
                        int gm = mbase + wm * 64 + mt * 16 + quad * 4 + r;
                        int b = gm >> 10, t = gm & 1023;
                        ks[(((size_t)(b * 16 + h)) << 10) + t] = s;
                    }
                }
        }
    }
}

// ---------------------------------------------------------------------------
// attn10: attn8 (best: 8 waves, q-tile 128, 4 blocks/CU) + two additive
// levers, structure untouched:
//  1. mraw prefetch: iteration i+1's mask loads issued right AFTER barrier 2
//     of iteration i -> their ~300-500cy L3 latency hides under compute
//     (attn8 issued them just before barrier 1 = full drain every iter).
//  2. XCD-aware swizzle: 1D grid (1024), lin&7 = XCD (dispatch round-robin);
//     remap so all 8 q-blocks sharing one (b,h)'s K/V land on ONE XCD ->
//     K/V fetched ~once per XCD instead of 8x cross-XCD redundant.
//     Bijection: xcd=lin&7, s=lin>>3, bh=xcd*16+(s>>3), qb=s&7.
// Per-wave compute body byte-identical to attn8.
// ---------------------------------------------------------------------------
__global__ __launch_bounds__(512) void attn10(const u16* __restrict__ qbuf,
                                              const u16* __restrict__ kbuf,
                                              const u16* __restrict__ vT,
                                              const float* __restrict__ ksum,
                                              const u16* __restrict__ mb,
                                              u16* __restrict__ ctx) {
    __shared__ u16 Ksm[64 * 64];
    __shared__ u16 Vsm[64 * 64];
    __shared__ u16 Psm[8 * 16 * 72];
    __shared__ float sksm[64];
    __shared__ float lsm[128];
    int tid = threadIdx.x;
    int wave = tid >> 6, lane = tid & 63;
    int quad = lane >> 4, l16 = lane & 15;
    // XCD-aware bijective remap (1024 blocks, 8 XCDs, 16 bh-groups/XCD)
    int lin = blockIdx.x;
    int xcd = lin & 7, s = lin >> 3;
    int bh = xcd * 16 + (s >> 3);
    int qb = s & 7;
    int b = bh >> 4, h = bh & 15;
    const u16* qp = qbuf + (size_t)bh * 65536;
    const u16* kp = kbuf + (size_t)bh * 65536;
    const u16* vp = vT + (size_t)bh * 65536;
    const float* ksp = ksum + (size_t)bh * 1024;
    int q0 = qb * 128 + wave * 16;
    const u16* mbp = mb + ((size_t)b * 1024 + q0 + l16) * 1024;

    bf16x8 qf0 = *(const bf16x8*)(qp + (size_t)(q0 + l16) * 64 + quad * 8);
    bf16x8 qf1 = *(const bf16x8*)(qp + (size_t)(q0 + l16) * 64 + 32 + quad * 8);

    f32x4 oacc[4] = {};
    float lsum = 0.f;
    // staging geometry: wave stages 8 rows (one GLDS each for K and V);
    // lane -> row octet (lane>>3), XOR chunk swizzle (row&7 == r8 invariant)
    int r8 = lane >> 3;
    int sch = (lane & 7) ^ r8;
    u16* lK = Ksm + wave * 512;
    u16* lV = Vsm + wave * 512;
    const u16* gK0 = kp + (size_t)(wave * 8 + r8) * 64 + sch * 8;
    const u16* gV0 = vp + (size_t)(wave * 8 + r8) * 1024 + sch * 8;
    int sx = l16 & 7;
    u16* pw = &Psm[wave * 16 * 72];

    // prologue: mask operands for iteration 0
    bf16x4 mraw[4];
#pragma unroll
    for (int nt = 0; nt < 4; nt++)
        mraw[nt] = *(const bf16x4*)(mbp + nt * 16 + quad * 4);

    for (int kb = 0; kb < 1024; kb += 64) {
        __syncthreads();  // prev-iter LDS reads done (mraw arrived under compute)
        GLDS16(gK0 + (size_t)kb * 64, lK);
        GLDS16(gV0 + kb, lV);
        if (tid < 64) sksm[tid] = ksp[kb + tid];
        __syncthreads();  // staging visible

        // prefetch next iteration's mask operands (drain at NEXT barrier 1,
        // hidden under this iteration's compute)
        int kn = (kb < 960) ? kb + 64 : kb;
        bf16x4 mrawN[4];
#pragma unroll
        for (int nt = 0; nt < 4; nt++)
            mrawN[nt] = *(const bf16x4*)(mbp + kn + nt * 16 + quad * 4);

        // S^T = K.Q^T, accumulator pre-biased with exp2-domain offset
        f32x4 sacc[4];
#pragma unroll
        for (int nt = 0; nt < 4; nt++)
            sacc[nt] = f32x4{SOFT_OFF, SOFT_OFF, SOFT_OFF, SOFT_OFF};
#pragma unroll
        for (int nt = 0; nt < 4; nt++) {
            bf16x8 kf0 = *(const bf16x8*)&Ksm[(nt * 16 + l16) * 64 + (quad ^ sx) * 8];
            bf16x8 kf1 = *(const bf16x8*)&Ksm[(nt * 16 + l16) * 64 + ((4 + quad) ^ sx) * 8];
            sacc[nt] = MFMA(kf0, qf0, sacc[nt]);
            sacc[nt] = MFMA(kf1, qf1, sacc[nt]);
        }

        // p = unmasked ? exp2(s + bias*ksum + off) : 0 ; packed bf16 P write
#pragma unroll
        for (int nt = 0; nt < 4; nt++) {
            f32x4 k4 = *(const f32x4*)&sksm[nt * 16 + quad * 4];
            float p[4];
#pragma unroll
            for (int r = 0; r < 4; r++) {
                float f = bf2f((u16)mraw[nt][r]);
                float x = fmaf(f, k4[r], sacc[nt][r]);
                float e = fast_exp2(x);
                p[r] = (f > -1.0e29f) ? e : 0.f;
                lsum += p[r];
            }
            *(u32*)&pw[l16 * 72 + nt * 16 + quad * 4] = pack2bf(p[0], p[1]);
            *(u32*)&pw[l16 * 72 + nt * 16 + quad * 4 + 2] = pack2bf(p[2], p[3]);
        }

        // PV: O += P.V  (wave-private Psm round trip; DS ops in-order)
#pragma unroll
        for (int hs = 0; hs < 2; hs++) {
            bf16x8 pf = *(const bf16x8*)&pw[l16 * 72 + hs * 32 + quad * 8];
#pragma unroll
            for (int at = 0; at < 4; at++) {
                bf16x8 vf = *(const bf16x8*)&Vsm[(at * 16 + l16) * 64 +
                                                 ((hs * 4 + quad) ^ sx) * 8];
                oacc[at] = MFMA(pf, vf, oacc[at]);
            }
        }

        // rotate prefetched mask operands
#pragma unroll
        for (int nt = 0; nt < 4; nt++) mraw[nt] = mrawN[nt];
    }

    lsum += __shfl_xor(lsum, 16);
    lsum += __shfl_xor(lsum, 32);
    if (lane < 16) lsm[wave * 16 + lane] = lsum;
    __syncthreads();

#pragma unroll
    for (int r = 0; r < 4; r++) {
        float linv = 1.0f / lsm[wave * 16 + quad * 4 + r];
        int q = q0 + quad * 4 + r;
#pragma unroll
        for (int at = 0; at < 4; at++) {
            ctx[(((size_t)b * 1024 + q) * 16 + h) * 64 + at * 16 + l16] =
                f2bf(oacc[at][r] * linv);
        }
    }
}

// ---------------------------------------------------------------------------
// gemmo: output projection, M=8192 N=1024 K=1024, f32 C. Same staging as gemm5.
// ---------------------------------------------------------------------------
__global__ __launch_bounds__(256) void gemmo(const u16* __restrict__ A,
                                             const u16* __restrict__ BT,
                                             float* __restrict__ C) {
    __shared__ u16 Asm[128 * 64];
    __shared__ u16 Bsm[128 * 64];
    int tid = threadIdx.x;
    int wave = tid >> 6, lane = tid & 63;
    int quad = lane >> 4, l16 = lane & 15;
    int wm = wave >> 1, wn = wave & 1;
    int mbase = blockIdx.y * 128, nbase = blockIdx.x * 128;
    f32x4 acc[4][4] = {};
    int srow = wave * 32 + (lane >> 3);
    int schunk = (lane & 7) ^ (lane >> 3);
    const u16* gA = A + (size_t)(mbase + srow) * 1024 + schunk * 8;
    const u16* gB = BT + (size_t)(nbase + srow) * 1024 + schunk * 8;
    u16* lA = Asm + wave * 2048;
    u16* lB = Bsm + wave * 2048;
    int sx = l16 & 7;
    for (int k0 = 0; k0 < 1024; k0 += 64) {
        __syncthreads();
#pragma unroll
        for (int j = 0; j < 4; j++) GLDS16(gA + k0 + j * 8192, lA + j * 512);
#pragma unroll
        for (int j = 0; j < 4; j++) GLDS16(gB + k0 + j * 8192, lB + j * 512);
        __syncthreads();
#pragma unroll
        for (int kk = 0; kk < 2; kk++) {
            bf16x8 af[4], bfr[4];
#pragma unroll
            for (int mt = 0; mt < 4; mt++)
                af[mt] = *(const bf16x8*)&Asm[(wm * 64 + mt * 16 + l16) * 64 +
                                              ((kk * 4 + quad) ^ sx) * 8];
#pragma unroll
            for (int nt = 0; nt < 4; nt++)
                bfr[nt] = *(const bf16x8*)&Bsm[(wn * 64 + nt * 16 + l16) * 64 +
                                               ((kk * 4 + quad) ^ sx) * 8];
#pragma unroll
            for (int mt = 0; mt < 4; mt++)
#pragma unroll
                for (int nt = 0; nt < 4; nt++)
                    acc[mt][nt] = MFMA(af[mt], bfr[nt], acc[mt][nt]);
        }
    }
#pragma unroll
    for (int mt = 0; mt < 4; mt++)
#pragma unroll
        for (int nt = 0; nt < 4; nt++)
#pragma unroll
            for (int r = 0; r < 4; r++) {
                int gm = mbase + wm * 64 + mt * 16 + quad * 4 + r;
                int gn = nbase + wn * 64 + nt * 16 + l16;
                C[(size_t)gm * 1024 + gn] = acc[mt][nt][r];
            }
}

// ---------------------------------------------------------------------------
extern "C" void kernel_launch(void* const* d_in, const int* in_sizes, int n_in,
                              void* d_out, int out_size, void* d_ws, size_t ws_size,
                              hipStream_t stream) {
    const float* states = (const float*)d_in[0];
    const float* key_states = (const float*)d_in[1];
    const float* masks = (const float*)d_in[2];
    const int* abias = (const int*)d_in[3];
    const float* Wq = (const float*)d_in[4];
    const float* Wk = (const float*)d_in[5];
    const float* Wv = (const float*)d_in[6];
    const float* Wout = (const float*)d_in[7];
    const float* be = (const float*)d_in[8];
    const float* bsc = (const float*)d_in[9];

    char* ws = (char*)d_ws;
    size_t off = 0;
    auto alloc = [&](size_t n) { void* p = ws + off; off += (n + 255) & ~(size_t)255; return p; };
    u16* wT = (u16*)alloc(4ull * 1024 * 1024 * 2);          // [Wq|Wk|Wv|Wout]^T bf16 (8 MB)
    u16* sbf = (u16*)alloc((size_t)BB * TT * DD * 2);       // states bf16 (16 MB)
    u16* kbf = (u16*)alloc((size_t)BB * TT * DD * 2);       // key_states bf16 (16 MB)
    u16* qb_ = (u16*)alloc((size_t)BB * HH * TT * AA * 2);  // q [B,H,T,A] (16 MB)
    u16* kb_ = (u16*)alloc((size_t)BB * HH * TT * AA * 2);  // k [B,H,T,A] (16 MB)
    u16* vT_ = (u16*)alloc((size_t)BB * HH * AA * TT * 2);  // vT [B,H,A,T] (16 MB)
    float* ks_ = (float*)alloc((size_t)BB * HH * TT * 4);   // ksum (0.5 MB)
    u16* mb_ = (u16*)alloc((size_t)BB * TT * TT * 2);       // fused mask+bias bf16 (16 MB)

    u16* woT = wT + 3145728;
    int* idx_ = (int*)qb_;   // 32 MB over qb_+kb_ (contiguous, dead until gemm5)
    u16* ctx_ = sbf;         // sbf dead after Q projection

    // 1) fused prep: cvt x2 + mbinit + idx init + tr_w  (all independent)
    prep1<<<dim3(17408), 256, 0, stream>>>(states, key_states, masks, Wq, Wk, Wv,
                                           Wout, sbf, kbf, mb_, idx_, wT);
    // 2) deterministic scatter (last-edge-wins, masked cells excluded)
    scat_max<<<dim3(EE / 256), 256, 0, stream>>>(abias, idx_);
    scat_res<<<dim3(EE / 256), 256, 0, stream>>>(abias, idx_, be, bsc, mb_);
    // 3) fused QKV projection (+ksum epilogue, +V-transpose epilogue)
    gemm5<<<dim3(24, 64), 256, 0, stream>>>(sbf, kbf, wT, qb_, kb_, vT_, ks_);
    // 4) attention (attn8 shape + mraw prefetch + XCD swizzle)
    attn10<<<dim3(1024), 512, 0, stream>>>(qb_, kb_, vT_, ks_, mb_, ctx_);
    // 5) output projection -> d_out (f32)
    gemmo<<<dim3(8, 64), 256, 0, stream>>>(ctx_, woT, (float*)d_out);
}

// Round 8
// 386.153 us; speedup vs baseline: 1.0013x; 1.0013x over previous
//
#include <hip/hip_runtime.h>
#include <hip/hip_bf16.h>

// Problem dims (fixed)
#define BB 8
#define TT 1024
#define DD 1024
#define HH 16
#define AA 64
#define EE 262144

typedef unsigned short u16;
typedef unsigned int u32;
typedef short bf16x4 __attribute__((ext_vector_type(4)));
typedef short bf16x8 __attribute__((ext_vector_type(8)));
typedef float f32x4 __attribute__((ext_vector_type(4)));

__device__ __forceinline__ float bf2f(u16 u) {
    union { float f; u32 i; } c; c.i = ((u32)u) << 16; return c.f;
}
__device__ __forceinline__ u16 f2bf(float f) {
    union { float f; u32 i; } c; c.f = f;
    u32 x = c.i;
    return (u16)((x + 0x7FFFu + ((x >> 16) & 1u)) >> 16);
}
// packed 2xf32 -> 2xbf16 (v_cvt_pk_bf16_f32 on gfx950)
__device__ __forceinline__ u32 pack2bf(float a, float b) {
    union { __hip_bfloat162 h; u32 u; } c;
    c.h = __float22bfloat162_rn(float2{a, b});
    return c.u;
}
// native exp2 (v_exp_f32)
__device__ __forceinline__ float fast_exp2(float x) {
#if __has_builtin(__builtin_amdgcn_exp2f)
    return __builtin_amdgcn_exp2f(x);
#else
    float r;
    asm("v_exp_f32 %0, %1" : "=v"(r) : "v"(x));
    return r;
#endif
}

// log2(e) folded scales: softmax computed as exp2( log2e * (s/8 + bias*ksum/8 - 20) )
#define QSCALE 0.18033688f          // 0.125 * 1.44269504
#define SOFT_OFF -28.8539008f       // -20 * 1.44269504

// async 16B global->LDS (per-lane gptr; LDS dest = wave-uniform base + lane*16)
#define GLDS16(gp, lp)                                                        \
    __builtin_amdgcn_global_load_lds(                                         \
        (const __attribute__((address_space(1))) u32*)(const void*)(gp),      \
        (__attribute__((address_space(3))) u32*)(void*)(lp), 16, 0, 0)

#define MFMA(a, b, c) __builtin_amdgcn_mfma_f32_16x16x32_bf16((a), (b), (c), 0, 0, 0)

// ---------------------------------------------------------------------------
// prep1: fused independent prep work, partitioned by blockIdx.x
//  [0,4096)      cvt states -> sbf
//  [4096,8192)   cvt key_states -> kbf
//  [8192,12288)  mbinit (masks -> bf16 mb)
//  [12288,16384) idx init (-1)
//  [16384,17408) tr_w (4x 1024x1024 f32 -> bf16 transposed)
// ---------------------------------------------------------------------------
__global__ __launch_bounds__(256) void prep1(const float* __restrict__ states,
                                             const float* __restrict__ keys,
                                             const float* __restrict__ masks,
                                             const float* __restrict__ Wq,
                                             const float* __restrict__ Wk,
                                             const float* __restrict__ Wv,
                                             const float* __restrict__ Wout,
                                             u16* __restrict__ sbf,
                                             u16* __restrict__ kbf,
                                             u16* __restrict__ mb,
                                             int* __restrict__ idx,
                                             u16* __restrict__ wT) {
    __shared__ u16 t[64 * 72];
    int bi = blockIdx.x, tid = threadIdx.x;
    if (bi < 12288) {
        if (bi < 8192) {  // cvt
            const float* src = (bi < 4096) ? states : keys;
            u16* dst = (bi < 4096) ? sbf : kbf;
            size_t i = ((size_t)(bi & 4095) * 256 + tid) * 8;
            f32x4 a = *(const f32x4*)(src + i);
            f32x4 b = *(const f32x4*)(src + i + 4);
            u32 o[4];
            o[0] = pack2bf(a[0], a[1]);
            o[1] = pack2bf(a[2], a[3]);
            o[2] = pack2bf(b[0], b[1]);
            o[3] = pack2bf(b[2], b[3]);
            *(bf16x8*)(dst + i) = *(bf16x8*)o;
        } else {  // mbinit
            size_t i = ((size_t)(bi - 8192) * 256 + tid) * 8;
            f32x4 a = *(const f32x4*)(masks + i);
            f32x4 b = *(const f32x4*)(masks + i + 4);
            const u16 M = f2bf(-1.0e30f);
            bf16x8 o;
#pragma unroll
            for (int j = 0; j < 4; j++) {
                o[j] = (short)((a[j] != 0.f) ? M : 0);
                o[4 + j] = (short)((b[j] != 0.f) ? M : 0);
            }
            *(bf16x8*)(mb + i) = o;
        }
    } else if (bi < 16384) {  // idx init
        size_t i = ((size_t)(bi - 12288) * 256 + tid) * 8;
        int4 m1 = {-1, -1, -1, -1};
        *(int4*)(idx + i) = m1;
        *(int4*)(idx + i + 4) = m1;
    } else {  // tr_w
        int zb = bi - 16384;
        int z = zb >> 8, by = (zb >> 4) & 15, bx = zb & 15;
        const float* src = (z == 0) ? Wq : (z == 1) ? Wk : (z == 2) ? Wv : Wout;
        u16* dst = wT + (size_t)z * 1048576;
        int row0 = by * 64, col0 = bx * 64;
        int r = tid >> 2, c0 = (tid & 3) * 16;
        const float* sp = src + (size_t)(row0 + r) * 1024 + col0 + c0;
        f32x4 f0 = *(const f32x4*)(sp);
        f32x4 f1 = *(const f32x4*)(sp + 4);
        f32x4 f2_ = *(const f32x4*)(sp + 8);
        f32x4 f3 = *(const f32x4*)(sp + 12);
#pragma unroll
        for (int j = 0; j < 4; j++) {
            t[r * 72 + c0 + j] = f2bf(f0[j]);
            t[r * 72 + c0 + 4 + j] = f2bf(f1[j]);
            t[r * 72 + c0 + 8 + j] = f2bf(f2_[j]);
            t[r * 72 + c0 + 12 + j] = f2bf(f3[j]);
        }
        __syncthreads();
        bf16x8 o0, o1;
#pragma unroll
        for (int j = 0; j < 8; j++) o0[j] = (short)t[(c0 + j) * 72 + r];
#pragma unroll
        for (int j = 0; j < 8; j++) o1[j] = (short)t[(c0 + 8 + j) * 72 + r];
        *(bf16x8*)(dst + (size_t)(col0 + r) * 1024 + row0 + c0) = o0;
        *(bf16x8*)(dst + (size_t)(col0 + r) * 1024 + row0 + c0 + 8) = o1;
    }
}

// ---------------------------------------------------------------------------
// scatter pass 1 — last edge index wins (numpy semantics)
// ---------------------------------------------------------------------------
__global__ __launch_bounds__(256) void scat_max(const int* __restrict__ ab,
                                                int* __restrict__ idx) {
    int e = blockIdx.x * 256 + threadIdx.x;
    int4 rec = ((const int4*)ab)[e];
    atomicMax(&idx[((((size_t)rec.y << 10) + rec.z) << 10) + rec.w], e);
}

// scatter pass 2 — winner writes prescaled bf16 value (skip masked cells)
// proj prescaled by 0.125 * log2(e) to match exp2-based softmax.
__global__ __launch_bounds__(256) void scat_res(const int* __restrict__ ab,
                                                const int* __restrict__ idx,
                                                const float* __restrict__ be,
                                                const float* __restrict__ bsc,
                                                u16* __restrict__ mb) {
    __shared__ float proj[32];
    int tid = threadIdx.x;
    if (tid < 32) {
        float s = 0.f;
        for (int a = 0; a < 64; a++) s += be[tid * 64 + a] * bsc[a];
        proj[tid] = s * QSCALE;  // fold 1/sqrt(A) * log2(e)
    }
    __syncthreads();
    int e = blockIdx.x * 256 + tid;
    int4 rec = ((const int4*)ab)[e];
    size_t cell = ((((size_t)rec.y << 10) + rec.z) << 10) + rec.w;
    if (idx[cell] == e && bf2f(mb[cell]) > -1.0e29f) mb[cell] = f2bf(proj[rec.x]);
}

// ---------------------------------------------------------------------------
// gemm5: fused QKV projection. grid (24,64): mat = x>>3 (0=Q,1=K,2=V).
// 128x128 tile, BK=64, both operands via global_load_lds w/ global-side XOR
// chunk swizzle (conflict-free unpadded LDS reads).
// mat 0: qb [B,H,T,A] bf16, scaled 0.125*log2e (exp2 softmax).
// mat 1: kb [B,H,T,A] bf16 + ksum f32 (shuffle-reduced in epilogue).
// mat 2: vT [B,H,A,T] bf16 via LDS transpose epilogue.
// ---------------------------------------------------------------------------
__global__ __launch_bounds__(256) void gemm5(const u16* __restrict__ sbf,
                                             const u16* __restrict__ kbf,
                                             const u16* __restrict__ wT,
                                             u16* __restrict__ qb,
                                             u16* __restrict__ kb,
                                             u16* __restrict__ vT,
                                             float* __restrict__ ks) {
    __shared__ u16 smem[17408];  // 34816 B: staging [0,16384) u16, transpose 128x136
    int tid = threadIdx.x;
    int wave = tid >> 6, lane = tid & 63;
    int quad = lane >> 4, l16 = lane & 15;
    int wm = wave >> 1, wn = wave & 1;
    int mat = blockIdx.x >> 3;
    int nloc = (blockIdx.x & 7) * 128;
    int mbase = blockIdx.y * 128;
    const u16* A = (mat == 0) ? sbf : kbf;
    const u16* BT = wT + (size_t)mat * 1048576;
    u16* Asm = smem;
    u16* Bsm = smem + 8192;
    f32x4 acc[4][4] = {};
    int srow = wave * 32 + (lane >> 3);
    int schunk = (lane & 7) ^ (lane >> 3);
    const u16* gA = A + (size_t)(mbase + srow) * 1024 + schunk * 8;
    const u16* gB = BT + (size_t)(nloc + srow) * 1024 + schunk * 8;
    u16* lA = Asm + wave * 2048;
    u16* lB = Bsm + wave * 2048;
    int sx = l16 & 7;
    for (int k0 = 0; k0 < 1024; k0 += 64) {
        __syncthreads();
#pragma unroll
        for (int j = 0; j < 4; j++) GLDS16(gA + k0 + j * 8192, lA + j * 512);
#pragma unroll
        for (int j = 0; j < 4; j++) GLDS16(gB + k0 + j * 8192, lB + j * 512);
        __syncthreads();
#pragma unroll
        for (int kk = 0; kk < 2; kk++) {
            bf16x8 af[4], bfr[4];
#pragma unroll
            for (int mt = 0; mt < 4; mt++)
                af[mt] = *(const bf16x8*)&Asm[(wm * 64 + mt * 16 + l16) * 64 +
                                              ((kk * 4 + quad) ^ sx) * 8];
#pragma unroll
            for (int nt = 0; nt < 4; nt++)
                bfr[nt] = *(const bf16x8*)&Bsm[(wn * 64 + nt * 16 + l16) * 64 +
                                               ((kk * 4 + quad) ^ sx) * 8];
#pragma unroll
            for (int mt = 0; mt < 4; mt++)
#pragma unroll
                for (int nt = 0; nt < 4; nt++)
                    acc[mt][nt] = MFMA(af[mt], bfr[nt], acc[mt][nt]);
        }
    }

    if (mat == 2) {
        // V: transpose through LDS -> vT [B,H,A,T]
        __syncthreads();  // all waves done with staging LDS
#pragma unroll
        for (int mt = 0; mt < 4; mt++)
#pragma unroll
            for (int nt = 0; nt < 4; nt++)
#pragma unroll
                for (int r = 0; r < 4; r++) {
                    int rowl = wm * 64 + mt * 16 + quad * 4 + r;
                    int coll = wn * 64 + nt * 16 + l16;
                    smem[coll * 136 + rowl] = f2bf(acc[mt][nt][r]);
                }
        __syncthreads();
        int b = mbase >> 10, t0 = mbase & 1023;
        int c = tid >> 1, hf = tid & 1;
        int h = (nloc >> 6) + (c >> 6);
        int a = c & 63;
        u16* dst = vT + ((((size_t)(b * 16 + h)) * 64 + a) << 10) + t0 + hf * 64;
        const u16* srcl = smem + c * 136 + hf * 64;
#pragma unroll
        for (int j = 0; j < 8; j++) *(bf16x8*)(dst + j * 8) = *(const bf16x8*)(srcl + j * 8);
    } else {
        u16* dst = (mat == 0) ? qb : kb;
        float sc = (mat == 0) ? QSCALE : 1.0f;
#pragma unroll
        for (int mt = 0; mt < 4; mt++)
#pragma unroll
            for (int nt = 0; nt < 4; nt++)
#pragma unroll
                for (int r = 0; r < 4; r++) {
                    int gm = mbase + wm * 64 + mt * 16 + quad * 4 + r;
                    int gnl = nloc + wn * 64 + nt * 16 + l16;
                    int b = gm >> 10, t = gm & 1023, h = gnl >> 6, a = gnl & 63;
                    dst[(((size_t)(b * 16 + h) * 1024) + t) * 64 + a] =
                        f2bf(acc[mt][nt][r] * sc);
                }
        if (mat == 1) {
            // ksum[b,h,t] = sum_a K (f32 acc, pre-rounding)
            int h = (nloc + wn * 64) >> 6;
#pragma unroll
            for (int mt = 0; mt < 4; mt++)
#pragma unroll
                for (int r = 0; r < 4; r++) {
                    float s = acc[mt][0][r] + acc[mt][1][r] + acc[mt][2][r] + acc[mt][3][r];
                    s += __shfl_xor(s, 1);
                    s += __shfl_xor(s, 2);
                    s += __shfl_xor(s, 4);
                    s += __shfl_xor(s, 8);
                    if (l16 == 0) {
                        int gm = mbase + wm * 64 + mt * 16 + quad * 4 + r;
                        int b = gm >> 10, t = gm & 1023;
                        ks[(((size_t)(b * 16 + h)) << 10) + t] = s;
                    }
                }
        }
    }
}

// ---------------------------------------------------------------------------
// attn11: EXACT attn8 structure (8 waves, q-tile 128, grid (8,16,8),
// 4 blocks/CU — the measured best at 85.8 us) + ONE change, cleanly
// attributed: mraw (mask) loads for iteration i+1 are issued right AFTER
// barrier 2 of iteration i instead of immediately before barrier 1 of
// iteration i+1. Their ~300-500cy L3 latency then hides under the whole
// compute phase instead of being drained cold at barrier 1's implicit
// vmcnt(0). Same instruction stream otherwise; strictly earlier issue.
// NO XCD swizzle (R7: locality improved 3.6x but perf regressed 25us —
// kernel is latency-bound, not BW-bound).
// ---------------------------------------------------------------------------
__global__ __launch_bounds__(512) void attn11(const u16* __restrict__ qbuf,
                                              const u16* __restrict__ kbuf,
                                              const u16* __restrict__ vT,
                                              const float* __restrict__ ksum,
                                              const u16* __restrict__ mb,
                                              u16* __restrict__ ctx) {
    __shared__ u16 Ksm[64 * 64];
    __shared__ u16 Vsm[64 * 64];
    __shared__ u16 Psm[8 * 16 * 72];
    __shared__ float sksm[64];
    __shared__ float lsm[128];
    int tid = threadIdx.x;
    int wave = tid >> 6, lane = tid & 63;
    int quad = lane >> 4, l16 = lane & 15;
    int qb = blockIdx.x, h = blockIdx.y, b = blockIdx.z;
    int bh = b * 16 + h;
    const u16* qp = qbuf + (size_t)bh * 65536;
    const u16* kp = kbuf + (size_t)bh * 65536;
    const u16* vp = vT + (size_t)bh * 65536;
    const float* ksp = ksum + (size_t)bh * 1024;
    int q0 = qb * 128 + wave * 16;
    const u16* mbp = mb + ((size_t)b * 1024 + q0 + l16) * 1024;

    bf16x8 qf0 = *(const bf16x8*)(qp + (size_t)(q0 + l16) * 64 + quad * 8);
    bf16x8 qf1 = *(const bf16x8*)(qp + (size_t)(q0 + l16) * 64 + 32 + quad * 8);

    f32x4 oacc[4] = {};
    float lsum = 0.f;
    // staging geometry: wave stages 8 rows (one GLDS each for K and V);
    // lane -> row octet (lane>>3), XOR chunk swizzle (row&7 == r8 invariant)
    int r8 = lane >> 3;
    int sch = (lane & 7) ^ r8;
    u16* lK = Ksm + wave * 512;
    u16* lV = Vsm + wave * 512;
    const u16* gK0 = kp + (size_t)(wave * 8 + r8) * 64 + sch * 8;
    const u16* gV0 = vp + (size_t)(wave * 8 + r8) * 1024 + sch * 8;
    int sx = l16 & 7;
    u16* pw = &Psm[wave * 16 * 72];

    // prologue: mask operands for iteration 0
    bf16x4 mraw[4];
#pragma unroll
    for (int nt = 0; nt < 4; nt++)
        mraw[nt] = *(const bf16x4*)(mbp + nt * 16 + quad * 4);

    for (int kb = 0; kb < 1024; kb += 64) {
        __syncthreads();  // prev-iter LDS reads done (mraw arrived under compute)
        GLDS16(gK0 + (size_t)kb * 64, lK);
        GLDS16(gV0 + kb, lV);
        if (tid < 64) sksm[tid] = ksp[kb + tid];
        __syncthreads();  // staging visible

        // prefetch next iteration's mask operands (drain at NEXT barrier 1,
        // hidden under this iteration's compute)
        int kn = (kb < 960) ? kb + 64 : kb;
        bf16x4 mrawN[4];
#pragma unroll
        for (int nt = 0; nt < 4; nt++)
            mrawN[nt] = *(const bf16x4*)(mbp + kn + nt * 16 + quad * 4);

        // S^T = K.Q^T, accumulator pre-biased with exp2-domain offset
        f32x4 sacc[4];
#pragma unroll
        for (int nt = 0; nt < 4; nt++)
            sacc[nt] = f32x4{SOFT_OFF, SOFT_OFF, SOFT_OFF, SOFT_OFF};
#pragma unroll
        for (int nt = 0; nt < 4; nt++) {
            bf16x8 kf0 = *(const bf16x8*)&Ksm[(nt * 16 + l16) * 64 + (quad ^ sx) * 8];
            bf16x8 kf1 = *(const bf16x8*)&Ksm[(nt * 16 + l16) * 64 + ((4 + quad) ^ sx) * 8];
            sacc[nt] = MFMA(kf0, qf0, sacc[nt]);
            sacc[nt] = MFMA(kf1, qf1, sacc[nt]);
        }

        // p = unmasked ? exp2(s + bias*ksum + off) : 0 ; packed bf16 P write
#pragma unroll
        for (int nt = 0; nt < 4; nt++) {
            f32x4 k4 = *(const f32x4*)&sksm[nt * 16 + quad * 4];
            float p[4];
#pragma unroll
            for (int r = 0; r < 4; r++) {
                float f = bf2f((u16)mraw[nt][r]);
                float x = fmaf(f, k4[r], sacc[nt][r]);
                float e = fast_exp2(x);
                p[r] = (f > -1.0e29f) ? e : 0.f;
                lsum += p[r];
            }
            *(u32*)&pw[l16 * 72 + nt * 16 + quad * 4] = pack2bf(p[0], p[1]);
            *(u32*)&pw[l16 * 72 + nt * 16 + quad * 4 + 2] = pack2bf(p[2], p[3]);
        }

        // PV: O += P.V  (wave-private Psm round trip; DS ops in-order)
#pragma unroll
        for (int hs = 0; hs < 2; hs++) {
            bf16x8 pf = *(const bf16x8*)&pw[l16 * 72 + hs * 32 + quad * 8];
#pragma unroll
            for (int at = 0; at < 4; at++) {
                bf16x8 vf = *(const bf16x8*)&Vsm[(at * 16 + l16) * 64 +
                                                 ((hs * 4 + quad) ^ sx) * 8];
                oacc[at] = MFMA(pf, vf, oacc[at]);
            }
        }

        // rotate prefetched mask operands
#pragma unroll
        for (int nt = 0; nt < 4; nt++) mraw[nt] = mrawN[nt];
    }

    lsum += __shfl_xor(lsum, 16);
    lsum += __shfl_xor(lsum, 32);
    if (lane < 16) lsm[wave * 16 + lane] = lsum;
    __syncthreads();

#pragma unroll
    for (int r = 0; r < 4; r++) {
        float linv = 1.0f / lsm[wave * 16 + quad * 4 + r];
        int q = q0 + quad * 4 + r;
#pragma unroll
        for (int at = 0; at < 4; at++) {
            ctx[(((size_t)b * 1024 + q) * 16 + h) * 64 + at * 16 + l16] =
                f2bf(oacc[at][r] * linv);
        }
    }
}

// ---------------------------------------------------------------------------
// gemmo: output projection, M=8192 N=1024 K=1024, f32 C. Same staging as gemm5.
// ---------------------------------------------------------------------------
__global__ __launch_bounds__(256) void gemmo(const u16* __restrict__ A,
                                             const u16* __restrict__ BT,
                                             float* __restrict__ C) {
    __shared__ u16 Asm[128 * 64];
    __shared__ u16 Bsm[128 * 64];
    int tid = threadIdx.x;
    int wave = tid >> 6, lane = tid & 63;
    int quad = lane >> 4, l16 = lane & 15;
    int wm = wave >> 1, wn = wave & 1;
    int mbase = blockIdx.y * 128, nbase = blockIdx.x * 128;
    f32x4 acc[4][4] = {};
    int srow = wave * 32 + (lane >> 3);
    int schunk = (lane & 7) ^ (lane >> 3);
    const u16* gA = A + (size_t)(mbase + srow) * 1024 + schunk * 8;
    const u16* gB = BT + (size_t)(nbase + srow) * 1024 + schunk * 8;
    u16* lA = Asm + wave * 2048;
    u16* lB = Bsm + wave * 2048;
    int sx = l16 & 7;
    for (int k0 = 0; k0 < 1024; k0 += 64) {
        __syncthreads();
#pragma unroll
        for (int j = 0; j < 4; j++) GLDS16(gA + k0 + j * 8192, lA + j * 512);
#pragma unroll
        for (int j = 0; j < 4; j++) GLDS16(gB + k0 + j * 8192, lB + j * 512);
        __syncthreads();
#pragma unroll
        for (int kk = 0; kk < 2; kk++) {
            bf16x8 af[4], bfr[4];
#pragma unroll
            for (int mt = 0; mt < 4; mt++)
                af[mt] = *(const bf16x8*)&Asm[(wm * 64 + mt * 16 + l16) * 64 +
                                              ((kk * 4 + quad) ^ sx) * 8];
#pragma unroll
            for (int nt = 0; nt < 4; nt++)
                bfr[nt] = *(const bf16x8*)&Bsm[(wn * 64 + nt * 16 + l16) * 64 +
                                               ((kk * 4 + quad) ^ sx) * 8];
#pragma unroll
            for (int mt = 0; mt < 4; mt++)
#pragma unroll
                for (int nt = 0; nt < 4; nt++)
                    acc[mt][nt] = MFMA(af[mt], bfr[nt], acc[mt][nt]);
        }
    }
#pragma unroll
    for (int mt = 0; mt < 4; mt++)
#pragma unroll
        for (int nt = 0; nt < 4; nt++)
#pragma unroll
            for (int r = 0; r < 4; r++) {
                int gm = mbase + wm * 64 + mt * 16 + quad * 4 + r;
                int gn = nbase + wn * 64 + nt * 16 + l16;
                C[(size_t)gm * 1024 + gn] = acc[mt][nt][r];
            }
}

// ---------------------------------------------------------------------------
extern "C" void kernel_launch(void* const* d_in, const int* in_sizes, int n_in,
                              void* d_out, int out_size, void* d_ws, size_t ws_size,
                              hipStream_t stream) {
    const float* states = (const float*)d_in[0];
    const float* key_states = (const float*)d_in[1];
    const float* masks = (const float*)d_in[2];
    const int* abias = (const int*)d_in[3];
    const float* Wq = (const float*)d_in[4];
    const float* Wk = (const float*)d_in[5];
    const float* Wv = (const float*)d_in[6];
    const float* Wout = (const float*)d_in[7];
    const float* be = (const float*)d_in[8];
    const float* bsc = (const float*)d_in[9];

    char* ws = (char*)d_ws;
    size_t off = 0;
    auto alloc = [&](size_t n) { void* p = ws + off; off += (n + 255) & ~(size_t)255; return p; };
    u16* wT = (u16*)alloc(4ull * 1024 * 1024 * 2);          // [Wq|Wk|Wv|Wout]^T bf16 (8 MB)
    u16* sbf = (u16*)alloc((size_t)BB * TT * DD * 2);       // states bf16 (16 MB)
    u16* kbf = (u16*)alloc((size_t)BB * TT * DD * 2);       // key_states bf16 (16 MB)
    u16* qb_ = (u16*)alloc((size_t)BB * HH * TT * AA * 2);  // q [B,H,T,A] (16 MB)
    u16* kb_ = (u16*)alloc((size_t)BB * HH * TT * AA * 2);  // k [B,H,T,A] (16 MB)
    u16* vT_ = (u16*)alloc((size_t)BB * HH * AA * TT * 2);  // vT [B,H,A,T] (16 MB)
    float* ks_ = (float*)alloc((size_t)BB * HH * TT * 4);   // ksum (0.5 MB)
    u16* mb_ = (u16*)alloc((size_t)BB * TT * TT * 2);       // fused mask+bias bf16 (16 MB)

    u16* woT = wT + 3145728;
    int* idx_ = (int*)qb_;   // 32 MB over qb_+kb_ (contiguous, dead until gemm5)
    u16* ctx_ = sbf;         // sbf dead after Q projection

    // 1) fused prep: cvt x2 + mbinit + idx init + tr_w  (all independent)
    prep1<<<dim3(17408), 256, 0, stream>>>(states, key_states, masks, Wq, Wk, Wv,
                                           Wout, sbf, kbf, mb_, idx_, wT);
    // 2) deterministic scatter (last-edge-wins, masked cells excluded)
    scat_max<<<dim3(EE / 256), 256, 0, stream>>>(abias, idx_);
    scat_res<<<dim3(EE / 256), 256, 0, stream>>>(abias, idx_, be, bsc, mb_);
    // 3) fused QKV projection (+ksum epilogue, +V-transpose epilogue)
    gemm5<<<dim3(24, 64), 256, 0, stream>>>(sbf, kbf, wT, qb_, kb_, vT_, ks_);
    // 4) attention (attn8 shape + mraw prefetch ONLY — no swizzle)
    attn11<<<dim3(8, 16, 8), 512, 0, stream>>>(qb_, kb_, vT_, ks_, mb_, ctx_);
    // 5) output projection -> d_out (f32)
    gemmo<<<dim3(8, 64), 256, 0, stream>>>(ctx_, woT, (float*)d_out);
}

// Round 9
// 363.918 us; speedup vs baseline: 1.0625x; 1.0611x over previous
//
#include <hip/hip_runtime.h>
#include <hip/hip_bf16.h>

// Problem dims (fixed)
#define BB 8
#define TT 1024
#define DD 1024
#define HH 16
#define AA 64
#define EE 262144

typedef unsigned short u16;
typedef unsigned int u32;
typedef short bf16x4 __attribute__((ext_vector_type(4)));
typedef short bf16x8 __attribute__((ext_vector_type(8)));
typedef float f32x4 __attribute__((ext_vector_type(4)));
typedef u32 u32x2 __attribute__((ext_vector_type(2)));

__device__ __forceinline__ float bf2f(u16 u) {
    union { float f; u32 i; } c; c.i = ((u32)u) << 16; return c.f;
}
__device__ __forceinline__ u16 f2bf(float f) {
    union { float f; u32 i; } c; c.f = f;
    u32 x = c.i;
    return (u16)((x + 0x7FFFu + ((x >> 16) & 1u)) >> 16);
}
// packed 2xf32 -> 2xbf16 (v_cvt_pk_bf16_f32 on gfx950), RNE like f2bf
__device__ __forceinline__ u32 pack2bf(float a, float b) {
    union { __hip_bfloat162 h; u32 u; } c;
    c.h = __float22bfloat162_rn(float2{a, b});
    return c.u;
}
// native exp2 (v_exp_f32)
__device__ __forceinline__ float fast_exp2(float x) {
#if __has_builtin(__builtin_amdgcn_exp2f)
    return __builtin_amdgcn_exp2f(x);
#else
    float r;
    asm("v_exp_f32 %0, %1" : "=v"(r) : "v"(x));
    return r;
#endif
}

// log2(e) folded scales: softmax computed as exp2( log2e * (s/8 + bias*ksum/8 - 20) )
#define QSCALE 0.18033688f          // 0.125 * 1.44269504
#define SOFT_OFF -28.8539008f       // -20 * 1.44269504

// async 16B global->LDS (per-lane gptr; LDS dest = wave-uniform base + lane*16)
#define GLDS16(gp, lp)                                                        \
    __builtin_amdgcn_global_load_lds(                                         \
        (const __attribute__((address_space(1))) u32*)(const void*)(gp),      \
        (__attribute__((address_space(3))) u32*)(void*)(lp), 16, 0, 0)

#define MFMA(a, b, c) __builtin_amdgcn_mfma_f32_16x16x32_bf16((a), (b), (c), 0, 0, 0)

// ---------------------------------------------------------------------------
// prep1: fused independent prep work, partitioned by blockIdx.x
//  [0,4096)      cvt states -> sbf
//  [4096,8192)   cvt key_states -> kbf
//  [8192,12288)  mbinit (masks -> bf16 mb)
//  [12288,16384) idx init (-1)
//  [16384,17408) tr_w (4x 1024x1024 f32 -> bf16 transposed)
// ---------------------------------------------------------------------------
__global__ __launch_bounds__(256) void prep1(const float* __restrict__ states,
                                             const float* __restrict__ keys,
                                             const float* __restrict__ masks,
                                             const float* __restrict__ Wq,
                                             const float* __restrict__ Wk,
                                             const float* __restrict__ Wv,
                                             const float* __restrict__ Wout,
                                             u16* __restrict__ sbf,
                                             u16* __restrict__ kbf,
                                             u16* __restrict__ mb,
                                             int* __restrict__ idx,
                                             u16* __restrict__ wT) {
    __shared__ u16 t[64 * 72];
    int bi = blockIdx.x, tid = threadIdx.x;
    if (bi < 12288) {
        if (bi < 8192) {  // cvt
            const float* src = (bi < 4096) ? states : keys;
            u16* dst = (bi < 4096) ? sbf : kbf;
            size_t i = ((size_t)(bi & 4095) * 256 + tid) * 8;
            f32x4 a = *(const f32x4*)(src + i);
            f32x4 b = *(const f32x4*)(src + i + 4);
            u32 o[4];
            o[0] = pack2bf(a[0], a[1]);
            o[1] = pack2bf(a[2], a[3]);
            o[2] = pack2bf(b[0], b[1]);
            o[3] = pack2bf(b[2], b[3]);
            *(bf16x8*)(dst + i) = *(bf16x8*)o;
        } else {  // mbinit
            size_t i = ((size_t)(bi - 8192) * 256 + tid) * 8;
            f32x4 a = *(const f32x4*)(masks + i);
            f32x4 b = *(const f32x4*)(masks + i + 4);
            const u16 M = f2bf(-1.0e30f);
            bf16x8 o;
#pragma unroll
            for (int j = 0; j < 4; j++) {
                o[j] = (short)((a[j] != 0.f) ? M : 0);
                o[4 + j] = (short)((b[j] != 0.f) ? M : 0);
            }
            *(bf16x8*)(mb + i) = o;
        }
    } else if (bi < 16384) {  // idx init
        size_t i = ((size_t)(bi - 12288) * 256 + tid) * 8;
        int4 m1 = {-1, -1, -1, -1};
        *(int4*)(idx + i) = m1;
        *(int4*)(idx + i + 4) = m1;
    } else {  // tr_w
        int zb = bi - 16384;
        int z = zb >> 8, by = (zb >> 4) & 15, bx = zb & 15;
        const float* src = (z == 0) ? Wq : (z == 1) ? Wk : (z == 2) ? Wv : Wout;
        u16* dst = wT + (size_t)z * 1048576;
        int row0 = by * 64, col0 = bx * 64;
        int r = tid >> 2, c0 = (tid & 3) * 16;
        const float* sp = src + (size_t)(row0 + r) * 1024 + col0 + c0;
        f32x4 f0 = *(const f32x4*)(sp);
        f32x4 f1 = *(const f32x4*)(sp + 4);
        f32x4 f2_ = *(const f32x4*)(sp + 8);
        f32x4 f3 = *(const f32x4*)(sp + 12);
        // vectorized staging writes: 2x16B (byte off = 144*r + 2*c0, 16B-aligned)
        u32 o[8];
        o[0] = pack2bf(f0[0], f0[1]);
        o[1] = pack2bf(f0[2], f0[3]);
        o[2] = pack2bf(f1[0], f1[1]);
        o[3] = pack2bf(f1[2], f1[3]);
        o[4] = pack2bf(f2_[0], f2_[1]);
        o[5] = pack2bf(f2_[2], f2_[3]);
        o[6] = pack2bf(f3[0], f3[1]);
        o[7] = pack2bf(f3[2], f3[3]);
        *(bf16x8*)&t[r * 72 + c0] = *(bf16x8*)&o[0];
        *(bf16x8*)&t[r * 72 + c0 + 8] = *(bf16x8*)&o[4];
        __syncthreads();
        bf16x8 o0, o1;
#pragma unroll
        for (int j = 0; j < 8; j++) o0[j] = (short)t[(c0 + j) * 72 + r];
#pragma unroll
        for (int j = 0; j < 8; j++) o1[j] = (short)t[(c0 + 8 + j) * 72 + r];
        *(bf16x8*)(dst + (size_t)(col0 + r) * 1024 + row0 + c0) = o0;
        *(bf16x8*)(dst + (size_t)(col0 + r) * 1024 + row0 + c0 + 8) = o1;
    }
}

// ---------------------------------------------------------------------------
// scatter pass 1 — last edge index wins (numpy semantics)
// ---------------------------------------------------------------------------
__global__ __launch_bounds__(256) void scat_max(const int* __restrict__ ab,
                                                int* __restrict__ idx) {
    int e = blockIdx.x * 256 + threadIdx.x;
    int4 rec = ((const int4*)ab)[e];
    atomicMax(&idx[((((size_t)rec.y << 10) + rec.z) << 10) + rec.w], e);
}

// scatter pass 2 — winner writes prescaled bf16 value (skip masked cells)
// proj prescaled by 0.125 * log2(e) to match exp2-based softmax.
__global__ __launch_bounds__(256) void scat_res(const int* __restrict__ ab,
                                                const int* __restrict__ idx,
                                                const float* __restrict__ be,
                                                const float* __restrict__ bsc,
                                                u16* __restrict__ mb) {
    __shared__ float proj[32];
    int tid = threadIdx.x;
    if (tid < 32) {
        float s = 0.f;
        for (int a = 0; a < 64; a++) s += be[tid * 64 + a] * bsc[a];
        proj[tid] = s * QSCALE;  // fold 1/sqrt(A) * log2(e)
    }
    __syncthreads();
    int e = blockIdx.x * 256 + tid;
    int4 rec = ((const int4*)ab)[e];
    size_t cell = ((((size_t)rec.y << 10) + rec.z) << 10) + rec.w;
    if (idx[cell] == e && bf2f(mb[cell]) > -1.0e29f) mb[cell] = f2bf(proj[rec.x]);
}

// ---------------------------------------------------------------------------
// gemm5: fused QKV projection. grid (24,64): mat = x>>3 (0=Q,1=K,2=V).
// 128x128 tile, BK=64, both operands via global_load_lds w/ global-side XOR
// chunk swizzle (conflict-free unpadded LDS reads).
// mat 0: qb [B,H,T,A] bf16, scaled 0.125*log2e (exp2 softmax).
// mat 1: kb [B,H,T,A] bf16 + ksum f32 (shuffle-reduced in epilogue).
// mat 2: vT [B,H,A,T] bf16 via LDS transpose epilogue (8B packed writes).
// ---------------------------------------------------------------------------
__global__ __launch_bounds__(256) void gemm5(const u16* __restrict__ sbf,
                                             const u16* __restrict__ kbf,
                                             const u16* __restrict__ wT,
                                             u16* __restrict__ qb,
                                             u16* __restrict__ kb,
                                             u16* __restrict__ vT,
                                             float* __restrict__ ks) {
    __shared__ u16 smem[17408];  // 34816 B: staging [0,16384) u16, transpose 128x136
    int tid = threadIdx.x;
    int wave = tid >> 6, lane = tid & 63;
    int quad = lane >> 4, l16 = lane & 15;
    int wm = wave >> 1, wn = wave & 1;
    int mat = blockIdx.x >> 3;
    int nloc = (blockIdx.x & 7) * 128;
    int mbase = blockIdx.y * 128;
    const u16* A = (mat == 0) ? sbf : kbf;
    const u16* BT = wT + (size_t)mat * 1048576;
    u16* Asm = smem;
    u16* Bsm = smem + 8192;
    f32x4 acc[4][4] = {};
    int srow = wave * 32 + (lane >> 3);
    int schunk = (lane & 7) ^ (lane >> 3);
    const u16* gA = A + (size_t)(mbase + srow) * 1024 + schunk * 8;
    const u16* gB = BT + (size_t)(nloc + srow) * 1024 + schunk * 8;
    u16* lA = Asm + wave * 2048;
    u16* lB = Bsm + wave * 2048;
    int sx = l16 & 7;
    for (int k0 = 0; k0 < 1024; k0 += 64) {
        __syncthreads();
#pragma unroll
        for (int j = 0; j < 4; j++) GLDS16(gA + k0 + j * 8192, lA + j * 512);
#pragma unroll
        for (int j = 0; j < 4; j++) GLDS16(gB + k0 + j * 8192, lB + j * 512);
        __syncthreads();
#pragma unroll
        for (int kk = 0; kk < 2; kk++) {
            bf16x8 af[4], bfr[4];
#pragma unroll
            for (int mt = 0; mt < 4; mt++)
                af[mt] = *(const bf16x8*)&Asm[(wm * 64 + mt * 16 + l16) * 64 +
                                              ((kk * 4 + quad) ^ sx) * 8];
#pragma unroll
            for (int nt = 0; nt < 4; nt++)
                bfr[nt] = *(const bf16x8*)&Bsm[(wn * 64 + nt * 16 + l16) * 64 +
                                               ((kk * 4 + quad) ^ sx) * 8];
#pragma unroll
            for (int mt = 0; mt < 4; mt++)
#pragma unroll
                for (int nt = 0; nt < 4; nt++)
                    acc[mt][nt] = MFMA(af[mt], bfr[nt], acc[mt][nt]);
        }
    }

    if (mat == 2) {
        // V: transpose through LDS -> vT [B,H,A,T]
        __syncthreads();  // all waves done with staging LDS
#pragma unroll
        for (int mt = 0; mt < 4; mt++)
#pragma unroll
            for (int nt = 0; nt < 4; nt++) {
                // 4 rows consecutive in rowl -> one packed 8B write
                // byte off = 272*coll + 2*rowl, rowl%4==0 -> 8B aligned
                int rowl = wm * 64 + mt * 16 + quad * 4;
                int coll = wn * 64 + nt * 16 + l16;
                u32x2 pk;
                pk[0] = pack2bf(acc[mt][nt][0], acc[mt][nt][1]);
                pk[1] = pack2bf(acc[mt][nt][2], acc[mt][nt][3]);
                *(u32x2*)&smem[coll * 136 + rowl] = pk;
            }
        __syncthreads();
        int b = mbase >> 10, t0 = mbase & 1023;
        int c = tid >> 1, hf = tid & 1;
        int h = (nloc >> 6) + (c >> 6);
        int a = c & 63;
        u16* dst = vT + ((((size_t)(b * 16 + h)) * 64 + a) << 10) + t0 + hf * 64;
        const u16* srcl = smem + c * 136 + hf * 64;
#pragma unroll
        for (int j = 0; j < 8; j++) *(bf16x8*)(dst + j * 8) = *(const bf16x8*)(srcl + j * 8);
    } else {
        u16* dst = (mat == 0) ? qb : kb;
        float sc = (mat == 0) ? QSCALE : 1.0f;
#pragma unroll
        for (int mt = 0; mt < 4; mt++)
#pragma unroll
            for (int nt = 0; nt < 4; nt++)
#pragma unroll
                for (int r = 0; r < 4; r++) {
                    int gm = mbase + wm * 64 + mt * 16 + quad * 4 + r;
                    int gnl = nloc + wn * 64 + nt * 16 + l16;
                    int b = gm >> 10, t = gm & 1023, h = gnl >> 6, a = gnl & 63;
                    dst[(((size_t)(b * 16 + h) * 1024) + t) * 64 + a] =
                        f2bf(acc[mt][nt][r] * sc);
                }
        if (mat == 1) {
            // ksum[b,h,t] = sum_a K (f32 acc, pre-rounding)
            int h = (nloc + wn * 64) >> 6;
#pragma unroll
            for (int mt = 0; mt < 4; mt++)
#pragma unroll
                for (int r = 0; r < 4; r++) {
                    float s = acc[mt][0][r] + acc[mt][1][r] + acc[mt][2][r] + acc[mt][3][r];
                    s += __shfl_xor(s, 1);
                    s += __shfl_xor(s, 2);
                    s += __shfl_xor(s, 4);
                    s += __shfl_xor(s, 8);
                    if (l16 == 0) {
                        int gm = mbase + wm * 64 + mt * 16 + quad * 4 + r;
                        int b = gm >> 10, t = gm & 1023;
                        ks[(((size_t)(b * 16 + h)) << 10) + t] = s;
                    }
                }
        }
    }
}

// ---------------------------------------------------------------------------
// attn8 (REVERTED to R5 exact — measured best, 85.8 us): 8 waves, q-tile
// 128, grid (8,16,8), 4 blocks/CU, single-buffered GLDS staging, 2 barriers
// per k-block, mraw loads issued immediately before barrier 1 (their drain
// rides under the GLDS drain; R8 proved hoisting them costs 25 us).
// No XCD swizzle (R7/R8: neutral). Softmax in exp2 domain.
// ---------------------------------------------------------------------------
__global__ __launch_bounds__(512) void attn8(const u16* __restrict__ qbuf,
                                             const u16* __restrict__ kbuf,
                                             const u16* __restrict__ vT,
                                             const float* __restrict__ ksum,
                                             const u16* __restrict__ mb,
                                             u16* __restrict__ ctx) {
    __shared__ u16 Ksm[64 * 64];
    __shared__ u16 Vsm[64 * 64];
    __shared__ u16 Psm[8 * 16 * 72];
    __shared__ float sksm[64];
    __shared__ float lsm[128];
    int tid = threadIdx.x;
    int wave = tid >> 6, lane = tid & 63;
    int quad = lane >> 4, l16 = lane & 15;
    int qb = blockIdx.x, h = blockIdx.y, b = blockIdx.z;
    int bh = b * 16 + h;
    const u16* qp = qbuf + (size_t)bh * 65536;
    const u16* kp = kbuf + (size_t)bh * 65536;
    const u16* vp = vT + (size_t)bh * 65536;
    const float* ksp = ksum + (size_t)bh * 1024;
    int q0 = qb * 128 + wave * 16;
    const u16* mbp = mb + ((size_t)b * 1024 + q0 + l16) * 1024;

    bf16x8 qf0 = *(const bf16x8*)(qp + (size_t)(q0 + l16) * 64 + quad * 8);
    bf16x8 qf1 = *(const bf16x8*)(qp + (size_t)(q0 + l16) * 64 + 32 + quad * 8);

    f32x4 oacc[4] = {};
    float lsum = 0.f;
    // staging geometry: wave stages 8 rows (one GLDS each for K and V);
    // lane -> row octet (lane>>3), XOR chunk swizzle (row&7 == r8 invariant)
    int r8 = lane >> 3;
    int sch = (lane & 7) ^ r8;
    u16* lK = Ksm + wave * 512;
    u16* lV = Vsm + wave * 512;
    const u16* gK0 = kp + (size_t)(wave * 8 + r8) * 64 + sch * 8;
    const u16* gV0 = vp + (size_t)(wave * 8 + r8) * 1024 + sch * 8;
    int sx = l16 & 7;
    u16* pw = &Psm[wave * 16 * 72];

    for (int kb = 0; kb < 1024; kb += 64) {
        bf16x4 mraw[4];
#pragma unroll
        for (int nt = 0; nt < 4; nt++)
            mraw[nt] = *(const bf16x4*)(mbp + kb + nt * 16 + quad * 4);
        __syncthreads();  // prev-iter LDS reads done
        GLDS16(gK0 + (size_t)kb * 64, lK);
        GLDS16(gV0 + kb, lV);
        if (tid < 64) sksm[tid] = ksp[kb + tid];
        __syncthreads();  // staging visible

        // S^T = K.Q^T, accumulator pre-biased with exp2-domain offset
        f32x4 sacc[4];
#pragma unroll
        for (int nt = 0; nt < 4; nt++)
            sacc[nt] = f32x4{SOFT_OFF, SOFT_OFF, SOFT_OFF, SOFT_OFF};
#pragma unroll
        for (int nt = 0; nt < 4; nt++) {
            bf16x8 kf0 = *(const bf16x8*)&Ksm[(nt * 16 + l16) * 64 + (quad ^ sx) * 8];
            bf16x8 kf1 = *(const bf16x8*)&Ksm[(nt * 16 + l16) * 64 + ((4 + quad) ^ sx) * 8];
            sacc[nt] = MFMA(kf0, qf0, sacc[nt]);
            sacc[nt] = MFMA(kf1, qf1, sacc[nt]);
        }

        // p = unmasked ? exp2(s + bias*ksum + off) : 0 ; packed bf16 P write
#pragma unroll
        for (int nt = 0; nt < 4; nt++) {
            f32x4 k4 = *(const f32x4*)&sksm[nt * 16 + quad * 4];
            float p[4];
#pragma unroll
            for (int r = 0; r < 4; r++) {
                float f = bf2f((u16)mraw[nt][r]);
                float x = fmaf(f, k4[r], sacc[nt][r]);
                float e = fast_exp2(x);
                p[r] = (f > -1.0e29f) ? e : 0.f;
                lsum += p[r];
            }
            *(u32*)&pw[l16 * 72 + nt * 16 + quad * 4] = pack2bf(p[0], p[1]);
            *(u32*)&pw[l16 * 72 + nt * 16 + quad * 4 + 2] = pack2bf(p[2], p[3]);
        }

        // PV: O += P.V  (wave-private Psm round trip; DS ops in-order)
#pragma unroll
        for (int hs = 0; hs < 2; hs++) {
            bf16x8 pf = *(const bf16x8*)&pw[l16 * 72 + hs * 32 + quad * 8];
#pragma unroll
            for (int at = 0; at < 4; at++) {
                bf16x8 vf = *(const bf16x8*)&Vsm[(at * 16 + l16) * 64 +
                                                 ((hs * 4 + quad) ^ sx) * 8];
                oacc[at] = MFMA(pf, vf, oacc[at]);
            }
        }
    }

    lsum += __shfl_xor(lsum, 16);
    lsum += __shfl_xor(lsum, 32);
    if (lane < 16) lsm[wave * 16 + lane] = lsum;
    __syncthreads();

#pragma unroll
    for (int r = 0; r < 4; r++) {
        float linv = 1.0f / lsm[wave * 16 + quad * 4 + r];
        int q = q0 + quad * 4 + r;
#pragma unroll
        for (int at = 0; at < 4; at++) {
            ctx[(((size_t)b * 1024 + q) * 16 + h) * 64 + at * 16 + l16] =
                f2bf(oacc[at][r] * linv);
        }
    }
}

// ---------------------------------------------------------------------------
// gemmo: output projection, M=8192 N=1024 K=1024, f32 C. Same staging as gemm5.
// ---------------------------------------------------------------------------
__global__ __launch_bounds__(256) void gemmo(const u16* __restrict__ A,
                                             const u16* __restrict__ BT,
                                             float* __restrict__ C) {
    __shared__ u16 Asm[128 * 64];
    __shared__ u16 Bsm[128 * 64];
    int tid = threadIdx.x;
    int wave = tid >> 6, lane = tid & 63;
    int quad = lane >> 4, l16 = lane & 15;
    int wm = wave >> 1, wn = wave & 1;
    int mbase = blockIdx.y * 128, nbase = blockIdx.x * 128;
    f32x4 acc[4][4] = {};
    int srow = wave * 32 + (lane >> 3);
    int schunk = (lane & 7) ^ (lane >> 3);
    const u16* gA = A + (size_t)(mbase + srow) * 1024 + schunk * 8;
    const u16* gB = BT + (size_t)(nbase + srow) * 1024 + schunk * 8;
    u16* lA = Asm + wave * 2048;
    u16* lB = Bsm + wave * 2048;
    int sx = l16 & 7;
    for (int k0 = 0; k0 < 1024; k0 += 64) {
        __syncthreads();
#pragma unroll
        for (int j = 0; j < 4; j++) GLDS16(gA + k0 + j * 8192, lA + j * 512);
#pragma unroll
        for (int j = 0; j < 4; j++) GLDS16(gB + k0 + j * 8192, lB + j * 512);
        __syncthreads();
#pragma unroll
        for (int kk = 0; kk < 2; kk++) {
            bf16x8 af[4], bfr[4];
#pragma unroll
            for (int mt = 0; mt < 4; mt++)
                af[mt] = *(const bf16x8*)&Asm[(wm * 64 + mt * 16 + l16) * 64 +
                                              ((kk * 4 + quad) ^ sx) * 8];
#pragma unroll
            for (int nt = 0; nt < 4; nt++)
                bfr[nt] = *(const bf16x8*)&Bsm[(wn * 64 + nt * 16 + l16) * 64 +
                                               ((kk * 4 + quad) ^ sx) * 8];
#pragma unroll
            for (int mt = 0; mt < 4; mt++)
#pragma unroll
                for (int nt = 0; nt < 4; nt++)
                    acc[mt][nt] = MFMA(af[mt], bfr[nt], acc[mt][nt]);
        }
    }
#pragma unroll
    for (int mt = 0; mt < 4; mt++)
#pragma unroll
        for (int nt = 0; nt < 4; nt++)
#pragma unroll
            for (int r = 0; r < 4; r++) {
                int gm = mbase + wm * 64 + mt * 16 + quad * 4 + r;
                int gn = nbase + wn * 64 + nt * 16 + l16;
                C[(size_t)gm * 1024 + gn] = acc[mt][nt][r];
            }
}

// ---------------------------------------------------------------------------
extern "C" void kernel_launch(void* const* d_in, const int* in_sizes, int n_in,
                              void* d_out, int out_size, void* d_ws, size_t ws_size,
                              hipStream_t stream) {
    const float* states = (const float*)d_in[0];
    const float* key_states = (const float*)d_in[1];
    const float* masks = (const float*)d_in[2];
    const int* abias = (const int*)d_in[3];
    const float* Wq = (const float*)d_in[4];
    const float* Wk = (const float*)d_in[5];
    const float* Wv = (const float*)d_in[6];
    const float* Wout = (const float*)d_in[7];
    const float* be = (const float*)d_in[8];
    const float* bsc = (const float*)d_in[9];

    char* ws = (char*)d_ws;
    size_t off = 0;
    auto alloc = [&](size_t n) { void* p = ws + off; off += (n + 255) & ~(size_t)255; return p; };
    u16* wT = (u16*)alloc(4ull * 1024 * 1024 * 2);          // [Wq|Wk|Wv|Wout]^T bf16 (8 MB)
    u16* sbf = (u16*)alloc((size_t)BB * TT * DD * 2);       // states bf16 (16 MB)
    u16* kbf = (u16*)alloc((size_t)BB * TT * DD * 2);       // key_states bf16 (16 MB)
    u16* qb_ = (u16*)alloc((size_t)BB * HH * TT * AA * 2);  // q [B,H,T,A] (16 MB)
    u16* kb_ = (u16*)alloc((size_t)BB * HH * TT * AA * 2);  // k [B,H,T,A] (16 MB)
    u16* vT_ = (u16*)alloc((size_t)BB * HH * AA * TT * 2);  // vT [B,H,A,T] (16 MB)
    float* ks_ = (float*)alloc((size_t)BB * HH * TT * 4);   // ksum (0.5 MB)
    u16* mb_ = (u16*)alloc((size_t)BB * TT * TT * 2);       // fused mask+bias bf16 (16 MB)

    u16* woT = wT + 3145728;
    int* idx_ = (int*)qb_;   // 32 MB over qb_+kb_ (contiguous, dead until gemm5)
    u16* ctx_ = sbf;         // sbf dead after Q projection

    // 1) fused prep: cvt x2 + mbinit + idx init + tr_w  (all independent)
    prep1<<<dim3(17408), 256, 0, stream>>>(states, key_states, masks, Wq, Wk, Wv,
                                           Wout, sbf, kbf, mb_, idx_, wT);
    // 2) deterministic scatter (last-edge-wins, masked cells excluded)
    scat_max<<<dim3(EE / 256), 256, 0, stream>>>(abias, idx_);
    scat_res<<<dim3(EE / 256), 256, 0, stream>>>(abias, idx_, be, bsc, mb_);
    // 3) fused QKV projection (+ksum epilogue, +V-transpose epilogue)
    gemm5<<<dim3(24, 64), 256, 0, stream>>>(sbf, kbf, wT, qb_, kb_, vT_, ks_);
    // 4) attention (q-tile 128, 8 waves — R5 best config, reverted exactly)
    attn8<<<dim3(8, 16, 8), 512, 0, stream>>>(qb_, kb_, vT_, ks_, mb_, ctx_);
    // 5) output projection -> d_out (f32)
    gemmo<<<dim3(8, 64), 256, 0, stream>>>(ctx_, woT, (float*)d_out);
}

// Round 10
// 358.322 us; speedup vs baseline: 1.0790x; 1.0156x over previous
//
#include <hip/hip_runtime.h>
#include <hip/hip_bf16.h>

// Problem dims (fixed)
#define BB 8
#define TT 1024
#define DD 1024
#define HH 16
#define AA 64
#define EE 262144

typedef unsigned short u16;
typedef unsigned int u32;
typedef short bf16x4 __attribute__((ext_vector_type(4)));
typedef short bf16x8 __attribute__((ext_vector_type(8)));
typedef float f32x4 __attribute__((ext_vector_type(4)));
typedef u32 u32x2 __attribute__((ext_vector_type(2)));

__device__ __forceinline__ float bf2f(u16 u) {
    union { float f; u32 i; } c; c.i = ((u32)u) << 16; return c.f;
}
__device__ __forceinline__ u16 f2bf(float f) {
    union { float f; u32 i; } c; c.f = f;
    u32 x = c.i;
    return (u16)((x + 0x7FFFu + ((x >> 16) & 1u)) >> 16);
}
// packed 2xf32 -> 2xbf16 (v_cvt_pk_bf16_f32 on gfx950), RNE like f2bf
__device__ __forceinline__ u32 pack2bf(float a, float b) {
    union { __hip_bfloat162 h; u32 u; } c;
    c.h = __float22bfloat162_rn(float2{a, b});
    return c.u;
}
// native exp2 (v_exp_f32)
__device__ __forceinline__ float fast_exp2(float x) {
#if __has_builtin(__builtin_amdgcn_exp2f)
    return __builtin_amdgcn_exp2f(x);
#else
    float r;
    asm("v_exp_f32 %0, %1" : "=v"(r) : "v"(x));
    return r;
#endif
}

// log2(e) folded scales: softmax computed as exp2( log2e * (s/8 + bias*ksum/8 - 20) )
#define QSCALE 0.18033688f          // 0.125 * 1.44269504
#define SOFT_OFF -28.8539008f       // -20 * 1.44269504

// async 16B global->LDS (per-lane gptr; LDS dest = wave-uniform base + lane*16)
#define GLDS16(gp, lp)                                                        \
    __builtin_amdgcn_global_load_lds(                                         \
        (const __attribute__((address_space(1))) u32*)(const void*)(gp),      \
        (__attribute__((address_space(3))) u32*)(void*)(lp), 16, 0, 0)

#define MFMA(a, b, c) __builtin_amdgcn_mfma_f32_16x16x32_bf16((a), (b), (c), 0, 0, 0)

// ---------------------------------------------------------------------------
// prep1: fused independent prep work, partitioned by blockIdx.x
//  [0,4096)      cvt states -> sbf
//  [4096,8192)   cvt key_states -> kbf
//  [8192,12288)  mbinit (masks -> bf16 mb)
//  [12288,16384) idx init (-1)
//  [16384,17408) tr_w (4x 1024x1024 f32 -> bf16 transposed)
// ---------------------------------------------------------------------------
__global__ __launch_bounds__(256) void prep1(const float* __restrict__ states,
                                             const float* __restrict__ keys,
                                             const float* __restrict__ masks,
                                             const float* __restrict__ Wq,
                                             const float* __restrict__ Wk,
                                             const float* __restrict__ Wv,
                                             const float* __restrict__ Wout,
                                             u16* __restrict__ sbf,
                                             u16* __restrict__ kbf,
                                             u16* __restrict__ mb,
                                             int* __restrict__ idx,
                                             u16* __restrict__ wT) {
    __shared__ u16 t[64 * 72];
    int bi = blockIdx.x, tid = threadIdx.x;
    if (bi < 12288) {
        if (bi < 8192) {  // cvt
            const float* src = (bi < 4096) ? states : keys;
            u16* dst = (bi < 4096) ? sbf : kbf;
            size_t i = ((size_t)(bi & 4095) * 256 + tid) * 8;
            f32x4 a = *(const f32x4*)(src + i);
            f32x4 b = *(const f32x4*)(src + i + 4);
            u32 o[4];
            o[0] = pack2bf(a[0], a[1]);
            o[1] = pack2bf(a[2], a[3]);
            o[2] = pack2bf(b[0], b[1]);
            o[3] = pack2bf(b[2], b[3]);
            *(bf16x8*)(dst + i) = *(bf16x8*)o;
        } else {  // mbinit
            size_t i = ((size_t)(bi - 8192) * 256 + tid) * 8;
            f32x4 a = *(const f32x4*)(masks + i);
            f32x4 b = *(const f32x4*)(masks + i + 4);
            const u16 M = f2bf(-1.0e30f);
            bf16x8 o;
#pragma unroll
            for (int j = 0; j < 4; j++) {
                o[j] = (short)((a[j] != 0.f) ? M : 0);
                o[4 + j] = (short)((b[j] != 0.f) ? M : 0);
            }
            *(bf16x8*)(mb + i) = o;
        }
    } else if (bi < 16384) {  // idx init
        size_t i = ((size_t)(bi - 12288) * 256 + tid) * 8;
        int4 m1 = {-1, -1, -1, -1};
        *(int4*)(idx + i) = m1;
        *(int4*)(idx + i + 4) = m1;
    } else {  // tr_w
        int zb = bi - 16384;
        int z = zb >> 8, by = (zb >> 4) & 15, bx = zb & 15;
        const float* src = (z == 0) ? Wq : (z == 1) ? Wk : (z == 2) ? Wv : Wout;
        u16* dst = wT + (size_t)z * 1048576;
        int row0 = by * 64, col0 = bx * 64;
        int r = tid >> 2, c0 = (tid & 3) * 16;
        const float* sp = src + (size_t)(row0 + r) * 1024 + col0 + c0;
        f32x4 f0 = *(const f32x4*)(sp);
        f32x4 f1 = *(const f32x4*)(sp + 4);
        f32x4 f2_ = *(const f32x4*)(sp + 8);
        f32x4 f3 = *(const f32x4*)(sp + 12);
        // vectorized staging writes: 2x16B (byte off = 144*r + 2*c0, 16B-aligned)
        u32 o[8];
        o[0] = pack2bf(f0[0], f0[1]);
        o[1] = pack2bf(f0[2], f0[3]);
        o[2] = pack2bf(f1[0], f1[1]);
        o[3] = pack2bf(f1[2], f1[3]);
        o[4] = pack2bf(f2_[0], f2_[1]);
        o[5] = pack2bf(f2_[2], f2_[3]);
        o[6] = pack2bf(f3[0], f3[1]);
        o[7] = pack2bf(f3[2], f3[3]);
        *(bf16x8*)&t[r * 72 + c0] = *(bf16x8*)&o[0];
        *(bf16x8*)&t[r * 72 + c0 + 8] = *(bf16x8*)&o[4];
        __syncthreads();
        bf16x8 o0, o1;
#pragma unroll
        for (int j = 0; j < 8; j++) o0[j] = (short)t[(c0 + j) * 72 + r];
#pragma unroll
        for (int j = 0; j < 8; j++) o1[j] = (short)t[(c0 + 8 + j) * 72 + r];
        *(bf16x8*)(dst + (size_t)(col0 + r) * 1024 + row0 + c0) = o0;
        *(bf16x8*)(dst + (size_t)(col0 + r) * 1024 + row0 + c0 + 8) = o1;
    }
}

// ---------------------------------------------------------------------------
// scatter pass 1 — last edge index wins (numpy semantics)
// ---------------------------------------------------------------------------
__global__ __launch_bounds__(256) void scat_max(const int* __restrict__ ab,
                                                int* __restrict__ idx) {
    int e = blockIdx.x * 256 + threadIdx.x;
    int4 rec = ((const int4*)ab)[e];
    atomicMax(&idx[((((size_t)rec.y << 10) + rec.z) << 10) + rec.w], e);
}

// scatter pass 2 — winner writes prescaled bf16 value (skip masked cells)
// proj prescaled by 0.125 * log2(e) to match exp2-based softmax.
__global__ __launch_bounds__(256) void scat_res(const int* __restrict__ ab,
                                                const int* __restrict__ idx,
                                                const float* __restrict__ be,
                                                const float* __restrict__ bsc,
                                                u16* __restrict__ mb) {
    __shared__ float proj[32];
    int tid = threadIdx.x;
    if (tid < 32) {
        float s = 0.f;
        for (int a = 0; a < 64; a++) s += be[tid * 64 + a] * bsc[a];
        proj[tid] = s * QSCALE;  // fold 1/sqrt(A) * log2(e)
    }
    __syncthreads();
    int e = blockIdx.x * 256 + tid;
    int4 rec = ((const int4*)ab)[e];
    size_t cell = ((((size_t)rec.y << 10) + rec.z) << 10) + rec.w;
    if (idx[cell] == e && bf2f(mb[cell]) > -1.0e29f) mb[cell] = f2bf(proj[rec.x]);
}

// ---------------------------------------------------------------------------
// gemm6: fused QKV projection, XCD-aware block remap. Work identical to
// gemm5; only the (mat,nloc,mbase) <- blockIdx mapping changed so the 8
// blocks sharing one A-row-panel (same mat,mbase; nloc 0..7) land on ONE
// XCD: lin = y*24+x (dispatch linear id, round-robin XCD = lin&7);
// c=lin&7, j=lin>>3: mat=j>>6, nloc=(j>>3)&7, mrow=((j&7)<<3)|c.
// Bijective; A-panel (256KB) fetched once per XCD instead of 8x.
// ---------------------------------------------------------------------------
__global__ __launch_bounds__(256) void gemm6(const u16* __restrict__ sbf,
                                             const u16* __restrict__ kbf,
                                             const u16* __restrict__ wT,
                                             u16* __restrict__ qb,
                                             u16* __restrict__ kb,
                                             u16* __restrict__ vT,
                                             float* __restrict__ ks) {
    __shared__ u16 smem[17408];  // 34816 B: staging [0,16384) u16, transpose 128x136
    int tid = threadIdx.x;
    int wave = tid >> 6, lane = tid & 63;
    int quad = lane >> 4, l16 = lane & 15;
    int wm = wave >> 1, wn = wave & 1;
    // XCD-aware bijective remap
    int lin = blockIdx.y * 24 + blockIdx.x;
    int c = lin & 7, j = lin >> 3;
    int mat = j >> 6;
    int nloc = ((j >> 3) & 7) * 128;
    int mbase = ((((j & 7) << 3) | c)) * 128;
    const u16* A = (mat == 0) ? sbf : kbf;
    const u16* BT = wT + (size_t)mat * 1048576;
    u16* Asm = smem;
    u16* Bsm = smem + 8192;
    f32x4 acc[4][4] = {};
    int srow = wave * 32 + (lane >> 3);
    int schunk = (lane & 7) ^ (lane >> 3);
    const u16* gA = A + (size_t)(mbase + srow) * 1024 + schunk * 8;
    const u16* gB = BT + (size_t)(nloc + srow) * 1024 + schunk * 8;
    u16* lA = Asm + wave * 2048;
    u16* lB = Bsm + wave * 2048;
    int sx = l16 & 7;
    for (int k0 = 0; k0 < 1024; k0 += 64) {
        __syncthreads();
#pragma unroll
        for (int j2 = 0; j2 < 4; j2++) GLDS16(gA + k0 + j2 * 8192, lA + j2 * 512);
#pragma unroll
        for (int j2 = 0; j2 < 4; j2++) GLDS16(gB + k0 + j2 * 8192, lB + j2 * 512);
        __syncthreads();
#pragma unroll
        for (int kk = 0; kk < 2; kk++) {
            bf16x8 af[4], bfr[4];
#pragma unroll
            for (int mt = 0; mt < 4; mt++)
                af[mt] = *(const bf16x8*)&Asm[(wm * 64 + mt * 16 + l16) * 64 +
                                              ((kk * 4 + quad) ^ sx) * 8];
#pragma unroll
            for (int nt = 0; nt < 4; nt++)
                bfr[nt] = *(const bf16x8*)&Bsm[(wn * 64 + nt * 16 + l16) * 64 +
                                               ((kk * 4 + quad) ^ sx) * 8];
#pragma unroll
            for (int mt = 0; mt < 4; mt++)
#pragma unroll
                for (int nt = 0; nt < 4; nt++)
                    acc[mt][nt] = MFMA(af[mt], bfr[nt], acc[mt][nt]);
        }
    }

    if (mat == 2) {
        // V: transpose through LDS -> vT [B,H,A,T]
        __syncthreads();  // all waves done with staging LDS
#pragma unroll
        for (int mt = 0; mt < 4; mt++)
#pragma unroll
            for (int nt = 0; nt < 4; nt++) {
                // 4 rows consecutive in rowl -> one packed 8B write
                int rowl = wm * 64 + mt * 16 + quad * 4;
                int coll = wn * 64 + nt * 16 + l16;
                u32x2 pk;
                pk[0] = pack2bf(acc[mt][nt][0], acc[mt][nt][1]);
                pk[1] = pack2bf(acc[mt][nt][2], acc[mt][nt][3]);
                *(u32x2*)&smem[coll * 136 + rowl] = pk;
            }
        __syncthreads();
        int b = mbase >> 10, t0 = mbase & 1023;
        int cc = tid >> 1, hf = tid & 1;
        int h = (nloc >> 6) + (cc >> 6);
        int a = cc & 63;
        u16* dst = vT + ((((size_t)(b * 16 + h)) * 64 + a) << 10) + t0 + hf * 64;
        const u16* srcl = smem + cc * 136 + hf * 64;
#pragma unroll
        for (int j2 = 0; j2 < 8; j2++)
            *(bf16x8*)(dst + j2 * 8) = *(const bf16x8*)(srcl + j2 * 8);
    } else {
        u16* dst = (mat == 0) ? qb : kb;
        float sc = (mat == 0) ? QSCALE : 1.0f;
#pragma unroll
        for (int mt = 0; mt < 4; mt++)
#pragma unroll
            for (int nt = 0; nt < 4; nt++)
#pragma unroll
                for (int r = 0; r < 4; r++) {
                    int gm = mbase + wm * 64 + mt * 16 + quad * 4 + r;
                    int gnl = nloc + wn * 64 + nt * 16 + l16;
                    int b = gm >> 10, t = gm & 1023, h = gnl >> 6, a = gnl & 63;
                    dst[(((size_t)(b * 16 + h) * 1024) + t) * 64 + a] =
                        f2bf(acc[mt][nt][r] * sc);
                }
        if (mat == 1) {
            // ksum[b,h,t] = sum_a K (f32 acc, pre-rounding)
            int h = (nloc + wn * 64) >> 6;
#pragma unroll
            for (int mt = 0; mt < 4; mt++)
#pragma unroll
                for (int r = 0; r < 4; r++) {
                    float s = acc[mt][0][r] + acc[mt][1][r] + acc[mt][2][r] + acc[mt][3][r];
                    s += __shfl_xor(s, 1);
                    s += __shfl_xor(s, 2);
                    s += __shfl_xor(s, 4);
                    s += __shfl_xor(s, 8);
                    if (l16 == 0) {
                        int gm = mbase + wm * 64 + mt * 16 + quad * 4 + r;
                        int b = gm >> 10, t = gm & 1023;
                        ks[(((size_t)(b * 16 + h)) << 10) + t] = s;
                    }
                }
        }
    }
}

// ---------------------------------------------------------------------------
// attn12: attn8 (R5 best structure: 8 waves, q-tile 128, grid (8,16,8),
// 4 blocks/CU, single-buffer staging, mraw loads just before barrier 1)
// + ONE change: lsum via MFMA ones-trick. lacc = MFMA(pf, ONES, lacc)
// rides the ~84%-idle matrix pipe; deletes 16 VALU adds/iter and the
// epilogue shuffle+lsm. lacc[r] = rowsum(q=quad*4+r), uniform across l16.
// (Unbundled from R4's confounders: sksm staging and P-write form kept.)
// ---------------------------------------------------------------------------
__global__ __launch_bounds__(512) void attn12(const u16* __restrict__ qbuf,
                                              const u16* __restrict__ kbuf,
                                              const u16* __restrict__ vT,
                                              const float* __restrict__ ksum,
                                              const u16* __restrict__ mb,
                                              u16* __restrict__ ctx) {
    __shared__ u16 Ksm[64 * 64];
    __shared__ u16 Vsm[64 * 64];
    __shared__ u16 Psm[8 * 16 * 72];
    __shared__ float sksm[64];
    int tid = threadIdx.x;
    int wave = tid >> 6, lane = tid & 63;
    int quad = lane >> 4, l16 = lane & 15;
    int qb = blockIdx.x, h = blockIdx.y, b = blockIdx.z;
    int bh = b * 16 + h;
    const u16* qp = qbuf + (size_t)bh * 65536;
    const u16* kp = kbuf + (size_t)bh * 65536;
    const u16* vp = vT + (size_t)bh * 65536;
    const float* ksp = ksum + (size_t)bh * 1024;
    int q0 = qb * 128 + wave * 16;
    const u16* mbp = mb + ((size_t)b * 1024 + q0 + l16) * 1024;

    bf16x8 qf0 = *(const bf16x8*)(qp + (size_t)(q0 + l16) * 64 + quad * 8);
    bf16x8 qf1 = *(const bf16x8*)(qp + (size_t)(q0 + l16) * 64 + 32 + quad * 8);

    // ones B-fragment for the MFMA row-sum (bf16 1.0)
    bf16x8 ONES;
#pragma unroll
    for (int j = 0; j < 8; j++) ONES[j] = (short)0x3F80;

    f32x4 oacc[4] = {};
    f32x4 lacc = {};
    // staging geometry: wave stages 8 rows (one GLDS each for K and V);
    // lane -> row octet (lane>>3), XOR chunk swizzle (row&7 == r8 invariant)
    int r8 = lane >> 3;
    int sch = (lane & 7) ^ r8;
    u16* lK = Ksm + wave * 512;
    u16* lV = Vsm + wave * 512;
    const u16* gK0 = kp + (size_t)(wave * 8 + r8) * 64 + sch * 8;
    const u16* gV0 = vp + (size_t)(wave * 8 + r8) * 1024 + sch * 8;
    int sx = l16 & 7;
    u16* pw = &Psm[wave * 16 * 72];

    for (int kb = 0; kb < 1024; kb += 64) {
        bf16x4 mraw[4];
#pragma unroll
        for (int nt = 0; nt < 4; nt++)
            mraw[nt] = *(const bf16x4*)(mbp + kb + nt * 16 + quad * 4);
        __syncthreads();  // prev-iter LDS reads done
        GLDS16(gK0 + (size_t)kb * 64, lK);
        GLDS16(gV0 + kb, lV);
        if (tid < 64) sksm[tid] = ksp[kb + tid];
        __syncthreads();  // staging visible

        // S^T = K.Q^T, accumulator pre-biased with exp2-domain offset
        f32x4 sacc[4];
#pragma unroll
        for (int nt = 0; nt < 4; nt++)
            sacc[nt] = f32x4{SOFT_OFF, SOFT_OFF, SOFT_OFF, SOFT_OFF};
#pragma unroll
        for (int nt = 0; nt < 4; nt++) {
            bf16x8 kf0 = *(const bf16x8*)&Ksm[(nt * 16 + l16) * 64 + (quad ^ sx) * 8];
            bf16x8 kf1 = *(const bf16x8*)&Ksm[(nt * 16 + l16) * 64 + ((4 + quad) ^ sx) * 8];
            sacc[nt] = MFMA(kf0, qf0, sacc[nt]);
            sacc[nt] = MFMA(kf1, qf1, sacc[nt]);
        }

        // p = unmasked ? exp2(s + bias*ksum + off) : 0 ; packed bf16 P write
#pragma unroll
        for (int nt = 0; nt < 4; nt++) {
            f32x4 k4 = *(const f32x4*)&sksm[nt * 16 + quad * 4];
            float p[4];
#pragma unroll
            for (int r = 0; r < 4; r++) {
                float f = bf2f((u16)mraw[nt][r]);
                float x = fmaf(f, k4[r], sacc[nt][r]);
                float e = fast_exp2(x);
                p[r] = (f > -1.0e29f) ? e : 0.f;
            }
            *(u32*)&pw[l16 * 72 + nt * 16 + quad * 4] = pack2bf(p[0], p[1]);
            *(u32*)&pw[l16 * 72 + nt * 16 + quad * 4 + 2] = pack2bf(p[2], p[3]);
        }

        // PV: O += P.V ; row-sum via ones-MFMA (wave-private Psm round trip)
#pragma unroll
        for (int hs = 0; hs < 2; hs++) {
            bf16x8 pf = *(const bf16x8*)&pw[l16 * 72 + hs * 32 + quad * 8];
            lacc = MFMA(pf, ONES, lacc);
#pragma unroll
            for (int at = 0; at < 4; at++) {
                bf16x8 vf = *(const bf16x8*)&Vsm[(at * 16 + l16) * 64 +
                                                 ((hs * 4 + quad) ^ sx) * 8];
                oacc[at] = MFMA(pf, vf, oacc[at]);
            }
        }
    }

    // lacc[r] = rowsum for q = q0 + quad*4 + r (uniform across l16)
#pragma unroll
    for (int r = 0; r < 4; r++) {
        float linv = 1.0f / lacc[r];
        int q = q0 + quad * 4 + r;
#pragma unroll
        for (int at = 0; at < 4; at++) {
            ctx[(((size_t)b * 1024 + q) * 16 + h) * 64 + at * 16 + l16] =
                f2bf(oacc[at][r] * linv);
        }
    }
}

// ---------------------------------------------------------------------------
// gemmo: output projection, M=8192 N=1024 K=1024, f32 C. Same staging as
// gemm6, same XCD-aware remap (grid (8,64): lin = y*8+x; c=lin&7, j=lin>>3;
// nbase=(j>>3)*128, mbase=(((j&7)<<3)|c)*128).
// ---------------------------------------------------------------------------
__global__ __launch_bounds__(256) void gemmo(const u16* __restrict__ A,
                                             const u16* __restrict__ BT,
                                             float* __restrict__ C) {
    __shared__ u16 Asm[128 * 64];
    __shared__ u16 Bsm[128 * 64];
    int tid = threadIdx.x;
    int wave = tid >> 6, lane = tid & 63;
    int quad = lane >> 4, l16 = lane & 15;
    int wm = wave >> 1, wn = wave & 1;
    int lin = blockIdx.y * 8 + blockIdx.x;
    int c = lin & 7, j = lin >> 3;
    int nbase = (j >> 3) * 128;
    int mbase = ((((j & 7) << 3) | c)) * 128;
    f32x4 acc[4][4] = {};
    int srow = wave * 32 + (lane >> 3);
    int schunk = (lane & 7) ^ (lane >> 3);
    const u16* gA = A + (size_t)(mbase + srow) * 1024 + schunk * 8;
    const u16* gB = BT + (size_t)(nbase + srow) * 1024 + schunk * 8;
    u16* lA = Asm + wave * 2048;
    u16* lB = Bsm + wave * 2048;
    int sx = l16 & 7;
    for (int k0 = 0; k0 < 1024; k0 += 64) {
        __syncthreads();
#pragma unroll
        for (int j2 = 0; j2 < 4; j2++) GLDS16(gA + k0 + j2 * 8192, lA + j2 * 512);
#pragma unroll
        for (int j2 = 0; j2 < 4; j2++) GLDS16(gB + k0 + j2 * 8192, lB + j2 * 512);
        __syncthreads();
#pragma unroll
        for (int kk = 0; kk < 2; kk++) {
            bf16x8 af[4], bfr[4];
#pragma unroll
            for (int mt = 0; mt < 4; mt++)
                af[mt] = *(const bf16x8*)&Asm[(wm * 64 + mt * 16 + l16) * 64 +
                                              ((kk * 4 + quad) ^ sx) * 8];
#pragma unroll
            for (int nt = 0; nt < 4; nt++)
                bfr[nt] = *(const bf16x8*)&Bsm[(wn * 64 + nt * 16 + l16) * 64 +
                                               ((kk * 4 + quad) ^ sx) * 8];
#pragma unroll
            for (int mt = 0; mt < 4; mt++)
#pragma unroll
                for (int nt = 0; nt < 4; nt++)
                    acc[mt][nt] = MFMA(af[mt], bfr[nt], acc[mt][nt]);
        }
    }
#pragma unroll
    for (int mt = 0; mt < 4; mt++)
#pragma unroll
        for (int nt = 0; nt < 4; nt++)
#pragma unroll
            for (int r = 0; r < 4; r++) {
                int gm = mbase + wm * 64 + mt * 16 + quad * 4 + r;
                int gn = nbase + wn * 64 + nt * 16 + l16;
                C[(size_t)gm * 1024 + gn] = acc[mt][nt][r];
            }
}

// ---------------------------------------------------------------------------
extern "C" void kernel_launch(void* const* d_in, const int* in_sizes, int n_in,
                              void* d_out, int out_size, void* d_ws, size_t ws_size,
                              hipStream_t stream) {
    const float* states = (const float*)d_in[0];
    const float* key_states = (const float*)d_in[1];
    const float* masks = (const float*)d_in[2];
    const int* abias = (const int*)d_in[3];
    const float* Wq = (const float*)d_in[4];
    const float* Wk = (const float*)d_in[5];
    const float* Wv = (const float*)d_in[6];
    const float* Wout = (const float*)d_in[7];
    const float* be = (const float*)d_in[8];
    const float* bsc = (const float*)d_in[9];

    char* ws = (char*)d_ws;
    size_t off = 0;
    auto alloc = [&](size_t n) { void* p = ws + off; off += (n + 255) & ~(size_t)255; return p; };
    u16* wT = (u16*)alloc(4ull * 1024 * 1024 * 2);          // [Wq|Wk|Wv|Wout]^T bf16 (8 MB)
    u16* sbf = (u16*)alloc((size_t)BB * TT * DD * 2);       // states bf16 (16 MB)
    u16* kbf = (u16*)alloc((size_t)BB * TT * DD * 2);       // key_states bf16 (16 MB)
    u16* qb_ = (u16*)alloc((size_t)BB * HH * TT * AA * 2);  // q [B,H,T,A] (16 MB)
    u16* kb_ = (u16*)alloc((size_t)BB * HH * TT * AA * 2);  // k [B,H,T,A] (16 MB)
    u16* vT_ = (u16*)alloc((size_t)BB * HH * AA * TT * 2);  // vT [B,H,A,T] (16 MB)
    float* ks_ = (float*)alloc((size_t)BB * HH * TT * 4);   // ksum (0.5 MB)
    u16* mb_ = (u16*)alloc((size_t)BB * TT * TT * 2);       // fused mask+bias bf16 (16 MB)

    u16* woT = wT + 3145728;
    int* idx_ = (int*)qb_;   // 32 MB over qb_+kb_ (contiguous, dead until gemm6)
    u16* ctx_ = sbf;         // sbf dead after Q projection

    // 1) fused prep: cvt x2 + mbinit + idx init + tr_w  (all independent)
    prep1<<<dim3(17408), 256, 0, stream>>>(states, key_states, masks, Wq, Wk, Wv,
                                           Wout, sbf, kbf, mb_, idx_, wT);
    // 2) deterministic scatter (last-edge-wins, masked cells excluded)
    scat_max<<<dim3(EE / 256), 256, 0, stream>>>(abias, idx_);
    scat_res<<<dim3(EE / 256), 256, 0, stream>>>(abias, idx_, be, bsc, mb_);
    // 3) fused QKV projection (XCD-aware remap)
    gemm6<<<dim3(24, 64), 256, 0, stream>>>(sbf, kbf, wT, qb_, kb_, vT_, ks_);
    // 4) attention (attn8 structure + ones-MFMA lsum)
    attn12<<<dim3(8, 16, 8), 512, 0, stream>>>(qb_, kb_, vT_, ks_, mb_, ctx_);
    // 5) output projection -> d_out (f32), XCD-aware remap
    gemmo<<<dim3(8, 64), 256, 0, stream>>>(ctx_, woT, (float*)d_out);
}

// Round 12
// 354.870 us; speedup vs baseline: 1.0895x; 1.0097x over previous
//
#include <hip/hip_runtime.h>
#include <hip/hip_bf16.h>

// Problem dims (fixed)
#define BB 8
#define TT 1024
#define DD 1024
#define HH 16
#define AA 64
#define EE 262144

typedef unsigned short u16;
typedef unsigned int u32;
typedef short bf16x4 __attribute__((ext_vector_type(4)));
typedef short bf16x8 __attribute__((ext_vector_type(8)));
typedef float f32x4 __attribute__((ext_vector_type(4)));
typedef u32 u32x2 __attribute__((ext_vector_type(2)));

__device__ __forceinline__ float bf2f(u16 u) {
    union { float f; u32 i; } c; c.i = ((u32)u) << 16; return c.f;
}
__device__ __forceinline__ u16 f2bf(float f) {
    union { float f; u32 i; } c; c.f = f;
    u32 x = c.i;
    return (u16)((x + 0x7FFFu + ((x >> 16) & 1u)) >> 16);
}
// packed 2xf32 -> 2xbf16 (v_cvt_pk_bf16_f32 on gfx950), RNE like f2bf
__device__ __forceinline__ u32 pack2bf(float a, float b) {
    union { __hip_bfloat162 h; u32 u; } c;
    c.h = __float22bfloat162_rn(float2{a, b});
    return c.u;
}
// native exp2 (v_exp_f32)
__device__ __forceinline__ float fast_exp2(float x) {
#if __has_builtin(__builtin_amdgcn_exp2f)
    return __builtin_amdgcn_exp2f(x);
#else
    float r;
    asm("v_exp_f32 %0, %1" : "=v"(r) : "v"(x));
    return r;
#endif
}

// log2(e) folded scales: softmax computed as exp2( log2e * (s/8 + bias*ksum/8 - 20) )
#define QSCALE 0.18033688f          // 0.125 * 1.44269504
#define SOFT_OFF -28.8539008f       // -20 * 1.44269504

// async 16B global->LDS (per-lane gptr; LDS dest = wave-uniform base + lane*16)
#define GLDS16(gp, lp)                                                        \
    __builtin_amdgcn_global_load_lds(                                         \
        (const __attribute__((address_space(1))) u32*)(const void*)(gp),      \
        (__attribute__((address_space(3))) u32*)(void*)(lp), 16, 0, 0)

#define MFMA(a, b, c) __builtin_amdgcn_mfma_f32_16x16x32_bf16((a), (b), (c), 0, 0, 0)

// ---------------------------------------------------------------------------
// prep1: fused independent prep work, partitioned by blockIdx.x
//  [0,4096)      cvt states -> sbf
//  [4096,8192)   cvt key_states -> kbf
//  [8192,12288)  mbinit (masks -> bf16 mb)
//  [12288,16384) idx init (-1)
//  [16384,17408) tr_w (4x 1024x1024 f32 -> bf16 transposed)
// ---------------------------------------------------------------------------
__global__ __launch_bounds__(256) void prep1(const float* __restrict__ states,
                                             const float* __restrict__ keys,
                                             const float* __restrict__ masks,
                                             const float* __restrict__ Wq,
                                             const float* __restrict__ Wk,
                                             const float* __restrict__ Wv,
                                             const float* __restrict__ Wout,
                                             u16* __restrict__ sbf,
                                             u16* __restrict__ kbf,
                                             u16* __restrict__ mb,
                                             int* __restrict__ idx,
                                             u16* __restrict__ wT) {
    __shared__ u16 t[64 * 72];
    int bi = blockIdx.x, tid = threadIdx.x;
    if (bi < 12288) {
        if (bi < 8192) {  // cvt
            const float* src = (bi < 4096) ? states : keys;
            u16* dst = (bi < 4096) ? sbf : kbf;
            size_t i = ((size_t)(bi & 4095) * 256 + tid) * 8;
            f32x4 a = *(const f32x4*)(src + i);
            f32x4 b = *(const f32x4*)(src + i + 4);
            u32 o[4];
            o[0] = pack2bf(a[0], a[1]);
            o[1] = pack2bf(a[2], a[3]);
            o[2] = pack2bf(b[0], b[1]);
            o[3] = pack2bf(b[2], b[3]);
            *(bf16x8*)(dst + i) = *(bf16x8*)o;
        } else {  // mbinit
            size_t i = ((size_t)(bi - 8192) * 256 + tid) * 8;
            f32x4 a = *(const f32x4*)(masks + i);
            f32x4 b = *(const f32x4*)(masks + i + 4);
            const u16 M = f2bf(-1.0e30f);
            bf16x8 o;
#pragma unroll
            for (int j = 0; j < 4; j++) {
                o[j] = (short)((a[j] != 0.f) ? M : 0);
                o[4 + j] = (short)((b[j] != 0.f) ? M : 0);
            }
            *(bf16x8*)(mb + i) = o;
        }
    } else if (bi < 16384) {  // idx init
        size_t i = ((size_t)(bi - 12288) * 256 + tid) * 8;
        int4 m1 = {-1, -1, -1, -1};
        *(int4*)(idx + i) = m1;
        *(int4*)(idx + i + 4) = m1;
    } else {  // tr_w
        int zb = bi - 16384;
        int z = zb >> 8, by = (zb >> 4) & 15, bx = zb & 15;
        const float* src = (z == 0) ? Wq : (z == 1) ? Wk : (z == 2) ? Wv : Wout;
        u16* dst = wT + (size_t)z * 1048576;
        int row0 = by * 64, col0 = bx * 64;
        int r = tid >> 2, c0 = (tid & 3) * 16;
        const float* sp = src + (size_t)(row0 + r) * 1024 + col0 + c0;
        f32x4 f0 = *(const f32x4*)(sp);
        f32x4 f1 = *(const f32x4*)(sp + 4);
        f32x4 f2_ = *(const f32x4*)(sp + 8);
        f32x4 f3 = *(const f32x4*)(sp + 12);
        // vectorized staging writes: 2x16B (byte off = 144*r + 2*c0, 16B-aligned)
        u32 o[8];
        o[0] = pack2bf(f0[0], f0[1]);
        o[1] = pack2bf(f0[2], f0[3]);
        o[2] = pack2bf(f1[0], f1[1]);
        o[3] = pack2bf(f1[2], f1[3]);
        o[4] = pack2bf(f2_[0], f2_[1]);
        o[5] = pack2bf(f2_[2], f2_[3]);
        o[6] = pack2bf(f3[0], f3[1]);
        o[7] = pack2bf(f3[2], f3[3]);
        *(bf16x8*)&t[r * 72 + c0] = *(bf16x8*)&o[0];
        *(bf16x8*)&t[r * 72 + c0 + 8] = *(bf16x8*)&o[4];
        __syncthreads();
        bf16x8 o0, o1;
#pragma unroll
        for (int j = 0; j < 8; j++) o0[j] = (short)t[(c0 + j) * 72 + r];
#pragma unroll
        for (int j = 0; j < 8; j++) o1[j] = (short)t[(c0 + 8 + j) * 72 + r];
        *(bf16x8*)(dst + (size_t)(col0 + r) * 1024 + row0 + c0) = o0;
        *(bf16x8*)(dst + (size_t)(col0 + r) * 1024 + row0 + c0 + 8) = o1;
    }
}

// ---------------------------------------------------------------------------
// scatter pass 1 — last edge index wins (numpy semantics)
// ---------------------------------------------------------------------------
__global__ __launch_bounds__(256) void scat_max(const int* __restrict__ ab,
                                                int* __restrict__ idx) {
    int e = blockIdx.x * 256 + threadIdx.x;
    int4 rec = ((const int4*)ab)[e];
    atomicMax(&idx[((((size_t)rec.y << 10) + rec.z) << 10) + rec.w], e);
}

// scatter pass 2 — winner writes prescaled bf16 value (skip masked cells)
// proj prescaled by 0.125 * log2(e) to match exp2-based softmax.
__global__ __launch_bounds__(256) void scat_res(const int* __restrict__ ab,
                                                const int* __restrict__ idx,
                                                const float* __restrict__ be,
                                                const float* __restrict__ bsc,
                                                u16* __restrict__ mb) {
    __shared__ float proj[32];
    int tid = threadIdx.x;
    if (tid < 32) {
        float s = 0.f;
        for (int a = 0; a < 64; a++) s += be[tid * 64 + a] * bsc[a];
        proj[tid] = s * QSCALE;  // fold 1/sqrt(A) * log2(e)
    }
    __syncthreads();
    int e = blockIdx.x * 256 + tid;
    int4 rec = ((const int4*)ab)[e];
    size_t cell = ((((size_t)rec.y << 10) + rec.z) << 10) + rec.w;
    if (idx[cell] == e && bf2f(mb[cell]) > -1.0e29f) mb[cell] = f2bf(proj[rec.x]);
}

// ---------------------------------------------------------------------------
// gemm6: fused QKV projection, XCD-aware block remap (kept from R10: non-attn
// 278.5 -> 269.0 us). Work identical to gemm5; only the (mat,nloc,mbase) <-
// blockIdx mapping changed so the 8 blocks sharing one A-row-panel land on
// ONE XCD: lin = y*24+x; c=lin&7, j=lin>>3: mat=j>>6, nloc=(j>>3)&7,
// mrow=((j&7)<<3)|c. Bijective; A-panel fetched once per XCD instead of 8x.
// ---------------------------------------------------------------------------
__global__ __launch_bounds__(256) void gemm6(const u16* __restrict__ sbf,
                                             const u16* __restrict__ kbf,
                                             const u16* __restrict__ wT,
                                             u16* __restrict__ qb,
                                             u16* __restrict__ kb,
                                             u16* __restrict__ vT,
                                             float* __restrict__ ks) {
    __shared__ u16 smem[17408];  // 34816 B: staging [0,16384) u16, transpose 128x136
    int tid = threadIdx.x;
    int wave = tid >> 6, lane = tid & 63;
    int quad = lane >> 4, l16 = lane & 15;
    int wm = wave >> 1, wn = wave & 1;
    // XCD-aware bijective remap
    int lin = blockIdx.y * 24 + blockIdx.x;
    int c = lin & 7, j = lin >> 3;
    int mat = j >> 6;
    int nloc = ((j >> 3) & 7) * 128;
    int mbase = ((((j & 7) << 3) | c)) * 128;
    const u16* A = (mat == 0) ? sbf : kbf;
    const u16* BT = wT + (size_t)mat * 1048576;
    u16* Asm = smem;
    u16* Bsm = smem + 8192;
    f32x4 acc[4][4] = {};
    int srow = wave * 32 + (lane >> 3);
    int schunk = (lane & 7) ^ (lane >> 3);
    const u16* gA = A + (size_t)(mbase + srow) * 1024 + schunk * 8;
    const u16* gB = BT + (size_t)(nloc + srow) * 1024 + schunk * 8;
    u16* lA = Asm + wave * 2048;
    u16* lB = Bsm + wave * 2048;
    int sx = l16 & 7;
    for (int k0 = 0; k0 < 1024; k0 += 64) {
        __syncthreads();
#pragma unroll
        for (int j2 = 0; j2 < 4; j2++) GLDS16(gA + k0 + j2 * 8192, lA + j2 * 512);
#pragma unroll
        for (int j2 = 0; j2 < 4; j2++) GLDS16(gB + k0 + j2 * 8192, lB + j2 * 512);
        __syncthreads();
#pragma unroll
        for (int kk = 0; kk < 2; kk++) {
            bf16x8 af[4], bfr[4];
#pragma unroll
            for (int mt = 0; mt < 4; mt++)
                af[mt] = *(const bf16x8*)&Asm[(wm * 64 + mt * 16 + l16) * 64 +
                                              ((kk * 4 + quad) ^ sx) * 8];
#pragma unroll
            for (int nt = 0; nt < 4; nt++)
                bfr[nt] = *(const bf16x8*)&Bsm[(wn * 64 + nt * 16 + l16) * 64 +
                                               ((kk * 4 + quad) ^ sx) * 8];
#pragma unroll
            for (int mt = 0; mt < 4; mt++)
#pragma unroll
                for (int nt = 0; nt < 4; nt++)
                    acc[mt][nt] = MFMA(af[mt], bfr[nt], acc[mt][nt]);
        }
    }

    if (mat == 2) {
        // V: transpose through LDS -> vT [B,H,A,T]
        __syncthreads();  // all waves done with staging LDS
#pragma unroll
        for (int mt = 0; mt < 4; mt++)
#pragma unroll
            for (int nt = 0; nt < 4; nt++) {
                // 4 rows consecutive in rowl -> one packed 8B write
                int rowl = wm * 64 + mt * 16 + quad * 4;
                int coll = wn * 64 + nt * 16 + l16;
                u32x2 pk;
                pk[0] = pack2bf(acc[mt][nt][0], acc[mt][nt][1]);
                pk[1] = pack2bf(acc[mt][nt][2], acc[mt][nt][3]);
                *(u32x2*)&smem[coll * 136 + rowl] = pk;
            }
        __syncthreads();
        int b = mbase >> 10, t0 = mbase & 1023;
        int cc = tid >> 1, hf = tid & 1;
        int h = (nloc >> 6) + (cc >> 6);
        int a = cc & 63;
        u16* dst = vT + ((((size_t)(b * 16 + h)) * 64 + a) << 10) + t0 + hf * 64;
        const u16* srcl = smem + cc * 136 + hf * 64;
#pragma unroll
        for (int j2 = 0; j2 < 8; j2++)
            *(bf16x8*)(dst + j2 * 8) = *(const bf16x8*)(srcl + j2 * 8);
    } else {
        u16* dst = (mat == 0) ? qb : kb;
        float sc = (mat == 0) ? QSCALE : 1.0f;
#pragma unroll
        for (int mt = 0; mt < 4; mt++)
#pragma unroll
            for (int nt = 0; nt < 4; nt++)
#pragma unroll
                for (int r = 0; r < 4; r++) {
                    int gm = mbase + wm * 64 + mt * 16 + quad * 4 + r;
                    int gnl = nloc + wn * 64 + nt * 16 + l16;
                    int b = gm >> 10, t = gm & 1023, h = gnl >> 6, a = gnl & 63;
                    dst[(((size_t)(b * 16 + h) * 1024) + t) * 64 + a] =
                        f2bf(acc[mt][nt][r] * sc);
                }
        if (mat == 1) {
            // ksum[b,h,t] = sum_a K (f32 acc, pre-rounding)
            int h = (nloc + wn * 64) >> 6;
#pragma unroll
            for (int mt = 0; mt < 4; mt++)
#pragma unroll
                for (int r = 0; r < 4; r++) {
                    float s = acc[mt][0][r] + acc[mt][1][r] + acc[mt][2][r] + acc[mt][3][r];
                    s += __shfl_xor(s, 1);
                    s += __shfl_xor(s, 2);
                    s += __shfl_xor(s, 4);
                    s += __shfl_xor(s, 8);
                    if (l16 == 0) {
                        int gm = mbase + wm * 64 + mt * 16 + quad * 4 + r;
                        int b = gm >> 10, t = gm & 1023;
                        ks[(((size_t)(b * 16 + h)) << 10) + t] = s;
                    }
                }
        }
    }
}

// ---------------------------------------------------------------------------
// attn8 (byte-exact R5/R9 best, 85.4 us): 8 waves, q-tile 128, grid
// (8,16,8), 4 blocks/CU, single-buffer staging, 2 barriers/k-block, mraw
// loads just before barrier 1 (drain rides under the GLDS drain — R8 proved
// hoisting costs 25 us), shuffle+lsm epilogue lsum (R10 proved ones-MFMA
// lsum costs 4 us: extra MFMAs sit on the critical path while the VALU adds
// co-issue free). No XCD swizzle (R7/R8: neutral for attn).
// ---------------------------------------------------------------------------
__global__ __launch_bounds__(512) void attn8(const u16* __restrict__ qbuf,
                                             const u16* __restrict__ kbuf,
                                             const u16* __restrict__ vT,
                                             const float* __restrict__ ksum,
                                             const u16* __restrict__ mb,
                                             u16* __restrict__ ctx) {
    __shared__ u16 Ksm[64 * 64];
    __shared__ u16 Vsm[64 * 64];
    __shared__ u16 Psm[8 * 16 * 72];
    __shared__ float sksm[64];
    __shared__ float lsm[128];
    int tid = threadIdx.x;
    int wave = tid >> 6, lane = tid & 63;
    int quad = lane >> 4, l16 = lane & 15;
    int qb = blockIdx.x, h = blockIdx.y, b = blockIdx.z;
    int bh = b * 16 + h;
    const u16* qp = qbuf + (size_t)bh * 65536;
    const u16* kp = kbuf + (size_t)bh * 65536;
    const u16* vp = vT + (size_t)bh * 65536;
    const float* ksp = ksum + (size_t)bh * 1024;
    int q0 = qb * 128 + wave * 16;
    const u16* mbp = mb + ((size_t)b * 1024 + q0 + l16) * 1024;

    bf16x8 qf0 = *(const bf16x8*)(qp + (size_t)(q0 + l16) * 64 + quad * 8);
    bf16x8 qf1 = *(const bf16x8*)(qp + (size_t)(q0 + l16) * 64 + 32 + quad * 8);

    f32x4 oacc[4] = {};
    float lsum = 0.f;
    // staging geometry: wave stages 8 rows (one GLDS each for K and V);
    // lane -> row octet (lane>>3), XOR chunk swizzle (row&7 == r8 invariant)
    int r8 = lane >> 3;
    int sch = (lane & 7) ^ r8;
    u16* lK = Ksm + wave * 512;
    u16* lV = Vsm + wave * 512;
    const u16* gK0 = kp + (size_t)(wave * 8 + r8) * 64 + sch * 8;
    const u16* gV0 = vp + (size_t)(wave * 8 + r8) * 1024 + sch * 8;
    int sx = l16 & 7;
    u16* pw = &Psm[wave * 16 * 72];

    for (int kb = 0; kb < 1024; kb += 64) {
        bf16x4 mraw[4];
#pragma unroll
        for (int nt = 0; nt < 4; nt++)
            mraw[nt] = *(const bf16x4*)(mbp + kb + nt * 16 + quad * 4);
        __syncthreads();  // prev-iter LDS reads done
        GLDS16(gK0 + (size_t)kb * 64, lK);
        GLDS16(gV0 + kb, lV);
        if (tid < 64) sksm[tid] = ksp[kb + tid];
        __syncthreads();  // staging visible

        // S^T = K.Q^T, accumulator pre-biased with exp2-domain offset
        f32x4 sacc[4];
#pragma unroll
        for (int nt = 0; nt < 4; nt++)
            sacc[nt] = f32x4{SOFT_OFF, SOFT_OFF, SOFT_OFF, SOFT_OFF};
#pragma unroll
        for (int nt = 0; nt < 4; nt++) {
            bf16x8 kf0 = *(const bf16x8*)&Ksm[(nt * 16 + l16) * 64 + (quad ^ sx) * 8];
            bf16x8 kf1 = *(const bf16x8*)&Ksm[(nt * 16 + l16) * 64 + ((4 + quad) ^ sx) * 8];
            sacc[nt] = MFMA(kf0, qf0, sacc[nt]);
            sacc[nt] = MFMA(kf1, qf1, sacc[nt]);
        }

        // p = unmasked ? exp2(s + bias*ksum + off) : 0 ; packed bf16 P write
#pragma unroll
        for (int nt = 0; nt < 4; nt++) {
            f32x4 k4 = *(const f32x4*)&sksm[nt * 16 + quad * 4];
            float p[4];
#pragma unroll
            for (int r = 0; r < 4; r++) {
                float f = bf2f((u16)mraw[nt][r]);
                float x = fmaf(f, k4[r], sacc[nt][r]);
                float e = fast_exp2(x);
                p[r] = (f > -1.0e29f) ? e : 0.f;
                lsum += p[r];
            }
            *(u32*)&pw[l16 * 72 + nt * 16 + quad * 4] = pack2bf(p[0], p[1]);
            *(u32*)&pw[l16 * 72 + nt * 16 + quad * 4 + 2] = pack2bf(p[2], p[3]);
        }

        // PV: O += P.V  (wave-private Psm round trip; DS ops in-order)
#pragma unroll
        for (int hs = 0; hs < 2; hs++) {
            bf16x8 pf = *(const bf16x8*)&pw[l16 * 72 + hs * 32 + quad * 8];
#pragma unroll
            for (int at = 0; at < 4; at++) {
                bf16x8 vf = *(const bf16x8*)&Vsm[(at * 16 + l16) * 64 +
                                                 ((hs * 4 + quad) ^ sx) * 8];
                oacc[at] = MFMA(pf, vf, oacc[at]);
            }
        }
    }

    lsum += __shfl_xor(lsum, 16);
    lsum += __shfl_xor(lsum, 32);
    if (lane < 16) lsm[wave * 16 + lane] = lsum;
    __syncthreads();

#pragma unroll
    for (int r = 0; r < 4; r++) {
        float linv = 1.0f / lsm[wave * 16 + quad * 4 + r];
        int q = q0 + quad * 4 + r;
#pragma unroll
        for (int at = 0; at < 4; at++) {
            ctx[(((size_t)b * 1024 + q) * 16 + h) * 64 + at * 16 + l16] =
                f2bf(oacc[at][r] * linv);
        }
    }
}

// ---------------------------------------------------------------------------
// gemmo: output projection, M=8192 N=1024 K=1024, f32 C. Same staging as
// gemm6, same XCD-aware remap (grid (8,64): lin = y*8+x; c=lin&7, j=lin>>3;
// nbase=(j>>3)*128, mbase=(((j&7)<<3)|c)*128).
// ---------------------------------------------------------------------------
__global__ __launch_bounds__(256) void gemmo(const u16* __restrict__ A,
                                             const u16* __restrict__ BT,
                                             float* __restrict__ C) {
    __shared__ u16 Asm[128 * 64];
    __shared__ u16 Bsm[128 * 64];
    int tid = threadIdx.x;
    int wave = tid >> 6, lane = tid & 63;
    int quad = lane >> 4, l16 = lane & 15;
    int wm = wave >> 1, wn = wave & 1;
    int lin = blockIdx.y * 8 + blockIdx.x;
    int c = lin & 7, j = lin >> 3;
    int nbase = (j >> 3) * 128;
    int mbase = ((((j & 7) << 3) | c)) * 128;
    f32x4 acc[4][4] = {};
    int srow = wave * 32 + (lane >> 3);
    int schunk = (lane & 7) ^ (lane >> 3);
    const u16* gA = A + (size_t)(mbase + srow) * 1024 + schunk * 8;
    const u16* gB = BT + (size_t)(nbase + srow) * 1024 + schunk * 8;
    u16* lA = Asm + wave * 2048;
    u16* lB = Bsm + wave * 2048;
    int sx = l16 & 7;
    for (int k0 = 0; k0 < 1024; k0 += 64) {
        __syncthreads();
#pragma unroll
        for (int j2 = 0; j2 < 4; j2++) GLDS16(gA + k0 + j2 * 8192, lA + j2 * 512);
#pragma unroll
        for (int j2 = 0; j2 < 4; j2++) GLDS16(gB + k0 + j2 * 8192, lB + j2 * 512);
        __syncthreads();
#pragma unroll
        for (int kk = 0; kk < 2; kk++) {
            bf16x8 af[4], bfr[4];
#pragma unroll
            for (int mt = 0; mt < 4; mt++)
                af[mt] = *(const bf16x8*)&Asm[(wm * 64 + mt * 16 + l16) * 64 +
                                              ((kk * 4 + quad) ^ sx) * 8];
#pragma unroll
            for (int nt = 0; nt < 4; nt++)
                bfr[nt] = *(const bf16x8*)&Bsm[(wn * 64 + nt * 16 + l16) * 64 +
                                               ((kk * 4 + quad) ^ sx) * 8];
#pragma unroll
            for (int mt = 0; mt < 4; mt++)
#pragma unroll
                for (int nt = 0; nt < 4; nt++)
                    acc[mt][nt] = MFMA(af[mt], bfr[nt], acc[mt][nt]);
        }
    }
#pragma unroll
    for (int mt = 0; mt < 4; mt++)
#pragma unroll
        for (int nt = 0; nt < 4; nt++)
#pragma unroll
            for (int r = 0; r < 4; r++) {
                int gm = mbase + wm * 64 + mt * 16 + quad * 4 + r;
                int gn = nbase + wn * 64 + nt * 16 + l16;
                C[(size_t)gm * 1024 + gn] = acc[mt][nt][r];
            }
}

// ---------------------------------------------------------------------------
extern "C" void kernel_launch(void* const* d_in, const int* in_sizes, int n_in,
                              void* d_out, int out_size, void* d_ws, size_t ws_size,
                              hipStream_t stream) {
    const float* states = (const float*)d_in[0];
    const float* key_states = (const float*)d_in[1];
    const float* masks = (const float*)d_in[2];
    const int* abias = (const int*)d_in[3];
    const float* Wq = (const float*)d_in[4];
    const float* Wk = (const float*)d_in[5];
    const float* Wv = (const float*)d_in[6];
    const float* Wout = (const float*)d_in[7];
    const float* be = (const float*)d_in[8];
    const float* bsc = (const float*)d_in[9];

    char* ws = (char*)d_ws;
    size_t off = 0;
    auto alloc = [&](size_t n) { void* p = ws + off; off += (n + 255) & ~(size_t)255; return p; };
    u16* wT = (u16*)alloc(4ull * 1024 * 1024 * 2);          // [Wq|Wk|Wv|Wout]^T bf16 (8 MB)
    u16* sbf = (u16*)alloc((size_t)BB * TT * DD * 2);       // states bf16 (16 MB)
    u16* kbf = (u16*)alloc((size_t)BB * TT * DD * 2);       // key_states bf16 (16 MB)
    u16* qb_ = (u16*)alloc((size_t)BB * HH * TT * AA * 2);  // q [B,H,T,A] (16 MB)
    u16* kb_ = (u16*)alloc((size_t)BB * HH * TT * AA * 2);  // k [B,H,T,A] (16 MB)
    u16* vT_ = (u16*)alloc((size_t)BB * HH * AA * TT * 2);  // vT [B,H,A,T] (16 MB)
    float* ks_ = (float*)alloc((size_t)BB * HH * TT * 4);   // ksum (0.5 MB)
    u16* mb_ = (u16*)alloc((size_t)BB * TT * TT * 2);       // fused mask+bias bf16 (16 MB)

    u16* woT = wT + 3145728;
    int* idx_ = (int*)qb_;   // 32 MB over qb_+kb_ (contiguous, dead until gemm6)
    u16* ctx_ = sbf;         // sbf dead after Q projection

    // 1) fused prep: cvt x2 + mbinit + idx init + tr_w  (all independent)
    prep1<<<dim3(17408), 256, 0, stream>>>(states, key_states, masks, Wq, Wk, Wv,
                                           Wout, sbf, kbf, mb_, idx_, wT);
    // 2) deterministic scatter (last-edge-wins, masked cells excluded)
    scat_max<<<dim3(EE / 256), 256, 0, stream>>>(abias, idx_);
    scat_res<<<dim3(EE / 256), 256, 0, stream>>>(abias, idx_, be, bsc, mb_);
    // 3) fused QKV projection (XCD-aware remap — kept, R10 win)
    gemm6<<<dim3(24, 64), 256, 0, stream>>>(sbf, kbf, wT, qb_, kb_, vT_, ks_);
    // 4) attention (attn8 — measured best, reverted byte-exact)
    attn8<<<dim3(8, 16, 8), 512, 0, stream>>>(qb_, kb_, vT_, ks_, mb_, ctx_);
    // 5) output projection -> d_out (f32), XCD-aware remap — kept
    gemmo<<<dim3(8, 64), 256, 0, stream>>>(ctx_, woT, (float*)d_out);
}